// Round 6
// baseline (413.159 us; speedup 1.0000x reference)
//
#include <hip/hip_runtime.h>
#include <hip/hip_bf16.h>
#include <math.h>

// ---------------- static problem config ----------------
#define BB 4
#define LL 4096
#define DD 1024
#define KK 32
#define HH 32
#define AA 4
#define CKK 4
#define DI 1024
#define ZC 2080            // 2*DI + KK
#define FLATC 1024         // K*H
#define BL (BB * LL)       // 16384
#define NPAD 2176          // W_in^T padded rows (17*128)
#define SEG 4              // L-segments per (b,k) chain in the fused kernels
#define FST 68             // fused LDS feature row stride (f32, 16B-aligned)

typedef unsigned short u16;
typedef __attribute__((ext_vector_type(8))) short s16x8;
typedef __attribute__((ext_vector_type(4))) float f32x4;

__device__ __forceinline__ u16 f2bf(float f) {
  union { float f; unsigned int u; } v; v.f = f;
  unsigned int r = (v.u + 0x7FFFu + ((v.u >> 16) & 1u)) >> 16;
  return (u16)r;
}
__device__ __forceinline__ float bf2f(u16 u) {
  union { unsigned int i; float f; } x; x.i = ((unsigned int)u) << 16; return x.f;
}
__device__ __forceinline__ void gl_lds16(const void* g, void* l) {
  __builtin_amdgcn_global_load_lds(
      (const __attribute__((address_space(1))) unsigned int*)g,
      (__attribute__((address_space(3))) unsigned int*)l, 16, 0, 0);
}

// ---------------- cast f32 -> bf16 (x) ----------------
__global__ __launch_bounds__(256) void cast_bf16_kernel(
    const float* __restrict__ src, u16* __restrict__ dst, int n) {
  const int i = (blockIdx.x * 256 + threadIdx.x) * 8;
  if (i >= n) return;
  float4 a = *(const float4*)(src + i);
  float4 b = *(const float4*)(src + i + 4);
  s16x8 v;
  v[0] = (short)f2bf(a.x); v[1] = (short)f2bf(a.y);
  v[2] = (short)f2bf(a.z); v[3] = (short)f2bf(a.w);
  v[4] = (short)f2bf(b.x); v[5] = (short)f2bf(b.y);
  v[6] = (short)f2bf(b.z); v[7] = (short)f2bf(b.w);
  *(s16x8*)(dst + i) = v;
}

// ---------------- transpose + cast: src[R][C] f32 -> dst[Cpad][R] bf16 ----
__global__ __launch_bounds__(256) void transpose_cast_kernel(
    const float* __restrict__ src, u16* __restrict__ dst,
    int R, int C, int Cpad) {
  __shared__ float t[32][33];
  const int tid = threadIdx.x;
  const int r0 = blockIdx.x * 32, c0 = blockIdx.y * 32;
  const int lr = tid >> 5, lc = tid & 31;
#pragma unroll
  for (int i = 0; i < 4; ++i) {
    const int r = r0 + i * 8 + lr, c = c0 + lc;
    float v = 0.f;
    if (r < R && c < C) v = src[(size_t)r * C + c];
    t[lc][i * 8 + lr] = v;
  }
  __syncthreads();
#pragma unroll
  for (int i = 0; i < 4; ++i) {
    const int dr = c0 + i * 8 + lr;   // row in dst = col in src
    const int dc = r0 + lc;           // col in dst = row in src
    if (dr < Cpad && dc < R) dst[(size_t)dr * R + dc] = f2bf(t[i * 8 + lr][lc]);
  }
}

// ---------------- 256x256 8-phase bf16 MFMA GEMM (T1+T2+T3+T4+T5) --------
// C[M,N] = A[M,K] * Bt[N,K]^T.  512 threads = 8 waves (2M x 4N), per-wave
// output 128x64 (8x4 fragments of 16x16), BK=64, NT = K/64 tiles (even).
// MODE 0: f32 linear C (ldc).  MODE 2: bf16 head-blocked z2 layout:
//   c<1024 -> z2x[(b*32 + (c>>5))*4096 + l][c&31],  c>=1024 -> z2g same
//   (b = row>>12, l = row&4095).  Writes stay 32B-chunked per fragment row.
//
// LDS 128KB: 8 half-regions of 16KB (128 rows x 64 cols bf16, row-major).
// 3-bit XOR swizzle: elem_col ^= (row&7)<<3; conflict-free (verified:
// SQ_LDS_BANK_CONFLICT 7.08M -> 0). global_load_lds writes linear dest,
// swizzle applied by pre-swizzling the GLOBAL source column (rule #21).
// Counted vmcnt(6) at phases 3/7 only; raw s_barrier (no vmcnt(0) drain).
#define FENCE() asm volatile("" ::: "memory")
#define SBAR() do { FENCE(); __builtin_amdgcn_s_barrier(); FENCE(); } while (0)
#define VMCNT6() asm volatile("s_waitcnt vmcnt(6)" ::: "memory")

#define RA(s, h) (((s) * 2 + (h)) * 8192)
#define RB(s, h) (32768 + ((s) * 2 + (h)) * 8192)

template <int MODE>
__global__ __launch_bounds__(512, 2) void gemm256_8ph(
    const u16* __restrict__ A, const u16* __restrict__ Bt, void* __restrict__ C,
    void* __restrict__ C2, int lda, int ldb, int ldc, int Kd, int Ncols) {
  __shared__ u16 lds[65536];   // 128 KiB
  const int tid = threadIdx.x;
  const int lane = tid & 63, wv = tid >> 6;
  const int wm = wv >> 2, wn = wv & 3;       // 2M x 4N wave grid
  const int lm = lane & 15, lq = lane >> 4;
  const int bm = blockIdx.x * 256, bn = blockIdx.y * 256;
  const int NT = Kd >> 6;                    // K tiles (even)
  const int NT2 = NT >> 1;

  const int rofs = wv * 8 + (lane >> 3);                 // region row
  const int cel = ((lane & 7) ^ (lane >> 3)) * 8;        // col elems, swz

  auto stageH = [&](const u16* __restrict__ G, int rowBase, int ld, int kt,
                    int regU16) {
    const u16* g0 = G + (size_t)(rowBase + rofs) * ld + (kt << 6) + cel;
    gl_lds16(g0, &lds[regU16 + wv * 512]);
    const u16* g1 = G + (size_t)(rowBase + 64 + rofs) * ld + (kt << 6) + cel;
    gl_lds16(g1, &lds[regU16 + 4096 + wv * 512]);
  };

  s16x8 Af[4][2], Bf[4][2];
  f32x4 acc[8][4];
  const f32x4 z4 = {0.f, 0.f, 0.f, 0.f};
#pragma unroll
  for (int i = 0; i < 8; ++i)
#pragma unroll
    for (int j = 0; j < 4; ++j) acc[i][j] = z4;

  const int xorw = (lm & 7) << 3;   // read-side swizzle XOR in u16 units

#define DSA(s, mh)                                                          \
  _Pragma("unroll") for (int f = 0; f < 4; ++f)                             \
  _Pragma("unroll") for (int ks = 0; ks < 2; ++ks)                          \
    Af[f][ks] = *(const s16x8*)&lds[RA(s, wm) +                             \
      (((((mh) * 4 + f) * 16 + lm) * 64 + ((ks * 32 + lq * 8) ^ xorw)))];

#define DSB(s)                                                              \
  _Pragma("unroll") for (int f = 0; f < 4; ++f)                             \
  _Pragma("unroll") for (int ks = 0; ks < 2; ++ks)                          \
    Bf[f][ks] = *(const s16x8*)&lds[RB(s, wn >> 1) +                        \
      ((((wn & 1) * 64 + f * 16 + lm) * 64 + ((ks * 32 + lq * 8) ^ xorw)))];

#define QUAD(mh, nh)                                                        \
  do {                                                                      \
    __builtin_amdgcn_s_setprio(1);                                          \
    _Pragma("unroll") for (int f = 0; f < 4; ++f)                           \
    _Pragma("unroll") for (int n = 0; n < 2; ++n)                           \
    _Pragma("unroll") for (int ks = 0; ks < 2; ++ks)                        \
      acc[(mh) * 4 + f][(nh) * 2 + n] =                                     \
          __builtin_amdgcn_mfma_f32_16x16x32_bf16(                          \
              Af[f][ks], Bf[(nh) * 2 + n][ks],                              \
              acc[(mh) * 4 + f][(nh) * 2 + n], 0, 0, 0);                    \
    __builtin_amdgcn_s_setprio(0);                                          \
  } while (0)

  // ---- prologue: 7 halves (t0 full + t1 B0,B1,A0); t1A1 comes at p0 ----
  stageH(A, bm, lda, 0, RA(0, 0));
  stageH(A, bm + 128, lda, 0, RA(0, 1));
  stageH(Bt, bn, ldb, 0, RB(0, 0));
  stageH(Bt, bn + 128, ldb, 0, RB(0, 1));
  stageH(Bt, bn, ldb, 1, RB(1, 0));
  stageH(Bt, bn + 128, ldb, 1, RB(1, 1));
  stageH(A, bm, lda, 1, RA(1, 0));
  VMCNT6();
  SBAR();

#pragma unroll 1
  for (int t = 0; t < NT2; ++t) {
    const int T2 = 2 * t + 2, T3 = 2 * t + 3;
    // -------- tile 2t from slot 0 --------
    DSA(0, 0); DSB(0);
    stageH(A, bm + 128, lda, 2 * t + 1, RA(1, 1));
    SBAR();
    QUAD(0, 0);
    SBAR();
    if (T2 < NT) stageH(Bt, bn, ldb, T2, RB(0, 0));
    SBAR();
    QUAD(0, 1);
    SBAR();
    DSA(0, 1);
    if (T2 < NT) stageH(Bt, bn + 128, ldb, T2, RB(0, 1));
    SBAR();
    QUAD(1, 0);
    SBAR();
    if (T2 < NT) stageH(A, bm, lda, T2, RA(0, 0));
    SBAR();
    QUAD(1, 1);
    VMCNT6();
    SBAR();
    // -------- tile 2t+1 from slot 1 --------
    DSA(1, 0); DSB(1);
    if (T2 < NT) stageH(A, bm + 128, lda, T2, RA(0, 1));
    SBAR();
    QUAD(0, 0);
    SBAR();
    if (T3 < NT) stageH(Bt, bn, ldb, T3, RB(1, 0));
    SBAR();
    QUAD(0, 1);
    SBAR();
    DSA(1, 1);
    if (T3 < NT) stageH(Bt, bn + 128, ldb, T3, RB(1, 1));
    SBAR();
    QUAD(1, 0);
    SBAR();
    if (T3 < NT) stageH(A, bm, lda, T3, RA(1, 0));
    SBAR();
    QUAD(1, 1);
    VMCNT6();
    SBAR();
  }

  // epilogue: D col = lm, row = lq*4 + r within each 16x16 fragment
#pragma unroll
  for (int f = 0; f < 8; ++f) {
#pragma unroll
    for (int n = 0; n < 4; ++n) {
      const int c = bn + wn * 64 + n * 16 + lm;
#pragma unroll
      for (int r = 0; r < 4; ++r) {
        const int row = bm + wm * 128 + f * 16 + lq * 4 + r;
        if (MODE == 0) {
          if (c < Ncols)
            ((float*)C)[(size_t)row * ldc + c] = acc[f][n][r];
        } else {
          const int b2 = row >> 12, l2 = row & 4095;
          const int k2 = (c >> 5) & 31, h2 = c & 31;
          u16* dst = (c < 1024) ? (u16*)C : (u16*)C2;
          dst[((size_t)(b2 * 32 + k2) * 4096 + l2) * 32 + h2] =
              f2bf(acc[f][n][r]);
        }
      }
    }
  }
#undef DSA
#undef DSB
#undef QUAD
}

// ---------------- score GEMM: z2s[bk][l] = x @ W_in[:,2048+k] ------------
__global__ __launch_bounds__(256) void score_gemm(
    const u16* __restrict__ A, const u16* __restrict__ Bt,
    u16* __restrict__ z2s) {
  __shared__ u16 As[8192];   // 128 rows x 64 k
  __shared__ u16 Bs[2048];   // 32 rows x 64 k
  const int tid = threadIdx.x;
  const int lane = tid & 63, wv = tid >> 6;
  const int lm = lane & 15, lq = lane >> 4;
  const int bm = blockIdx.x * 128;

  const f32x4 z4 = {0.f, 0.f, 0.f, 0.f};
  f32x4 acc[2][2];
#pragma unroll
  for (int i = 0; i < 2; ++i)
#pragma unroll
    for (int j = 0; j < 2; ++j) acc[i][j] = z4;

  for (int k0 = 0; k0 < DD; k0 += 64) {
    __syncthreads();
#pragma unroll
    for (int t = 0; t < 5; ++t) {
      const int idx = wv * 5 + t;            // 0..19
      if (idx < 16) {
        const int mt = idx >> 1, kt = idx & 1;
        const u16* g = A + (size_t)(bm + mt * 16 + lm) * DD + k0 + kt * 32 + lq * 8;
        gl_lds16(g, &As[idx * 512]);
      } else {
        const int bidx = idx - 16;
        const int nt = bidx >> 1, kt = bidx & 1;
        const u16* g = Bt + (size_t)(2048 + nt * 16 + lm) * DD + k0 + kt * 32 + lq * 8;
        gl_lds16(g, &Bs[bidx * 512]);
      }
    }
    __syncthreads();
#pragma unroll
    for (int kt = 0; kt < 2; ++kt) {
      s16x8 af[2], bfb[2];
#pragma unroll
      for (int i = 0; i < 2; ++i) {
        const int mt = wv * 2 + i;
        af[i] = *(const s16x8*)&As[(mt * 2 + kt) * 512 + lane * 8];
        bfb[i] = *(const s16x8*)&Bs[(i * 2 + kt) * 512 + lane * 8];
      }
#pragma unroll
      for (int i = 0; i < 2; ++i)
#pragma unroll
        for (int j = 0; j < 2; ++j)
          acc[i][j] = __builtin_amdgcn_mfma_f32_16x16x32_bf16(af[i], bfb[j], acc[i][j], 0, 0, 0);
    }
  }
#pragma unroll
  for (int i = 0; i < 2; ++i)
#pragma unroll
    for (int j = 0; j < 2; ++j)
#pragma unroll
      for (int r = 0; r < 4; ++r) {
        const int row = bm + wv * 32 + i * 16 + lq * 4 + r;
        const int b2 = row >> 12, l2 = row & 4095;
        const int k2 = j * 16 + lm;
        z2s[(size_t)(b2 * 32 + k2) * 4096 + l2] = f2bf(acc[i][j][r]);
      }
}

// ---------------- fused pass 0: per-(chain,segment) column totals ---------
// Block = (bk, s). Computes features for the 1024-row segment and reduces
// the 65 column sums (32 re + 32 im + den). No gate plane, no scan state.
// Deterministic: no inter-block communication (G16-safe; the round-5
// decoupled-lookback spin could deadlock when 512 blocks are not
// co-resident).
__global__ __launch_bounds__(256) void fuse_pass0(
    const u16* __restrict__ z2x, const u16* __restrict__ z2s,
    const float* __restrict__ kern, const float* __restrict__ theta,
    const float* __restrict__ decay, const float* __restrict__ anchor,
    const float* __restrict__ sscale, float* __restrict__ tot) {
  __shared__ u16 zx[67 * 32];
  __shared__ float zs[68];
  __shared__ float pw[64];
  __shared__ float kx[4][32], th[32];
  __shared__ float ks4[4];
  __shared__ float red[8][64];
  __shared__ float dred[64];

  const int tid = threadIdx.x;
  const int bk = blockIdx.x;            // b*32 + k
  const int s = blockIdx.y;
  const int k = bk & 31;
  const int rr = tid >> 5, h = tid & 31;
  const size_t pbase = (size_t)bk * 4096 * 32;
  const size_t sbase = (size_t)bk * 4096;

  if (tid < 128) {
    const int w_ = tid >> 5, c = tid & 31;
    kx[w_][c] = kern[w_ * ZC + k * 32 + c];
  }
  if (tid < 32) th[tid] = theta[k * 32 + tid];
  if (tid < 4) ks4[tid] = kern[tid * ZC + 2048 + k];
  const float slope = (k < KK - AA) ? decay[k] : anchor[k - (KK - AA)];
  const float sp = log1pf(__expf(slope));
  const float sk = sscale[k];
  __syncthreads();

  const int l0 = s * 1024;
  float sre_acc = 0.f, sim_acc = 0.f, den_acc = 0.f;

#pragma unroll 1
  for (int ch = 0; ch < 16; ++ch) {
    const int r0 = l0 + ch * 64;
    for (int u = tid; u < 268; u += 256) {
      const int row = u >> 2, q = u & 3;
      const int gl = r0 - 3 + row;
      s16x8 vx = {0, 0, 0, 0, 0, 0, 0, 0};
      if (gl >= 0) vx = *(const s16x8*)(z2x + pbase + (size_t)gl * 32 + q * 8);
      *(s16x8*)&zx[row * 32 + q * 8] = vx;
    }
    if (tid < 67) {
      const int gl = r0 - 3 + tid;
      zs[tid] = (gl >= 0) ? bf2f(z2s[sbase + gl]) : 0.f;
    }
    __syncthreads();
    if (tid < 64) {
      float v = zs[tid] * ks4[0];
      v = fmaf(zs[tid + 1], ks4[1], v);
      v = fmaf(zs[tid + 2], ks4[2], v);
      v = fmaf(zs[tid + 3], ks4[3], v);
      const int l = r0 + tid;
      const float lw = (k < KK - AA) ? (-sp * (float)(LL - 1 - l))
                                     : (-sp * (float)l);
      const float p = __expf(sk * v + lw);
      pw[tid] = p;
      den_acc += p;
    }
    __syncthreads();
#pragma unroll
    for (int rg = 0; rg < 8; ++rg) {
      const int r = rg * 8 + rr;
      float v = bf2f(zx[r * 32 + h]) * kx[0][h];
      v = fmaf(bf2f(zx[(r + 1) * 32 + h]), kx[1][h], v);
      v = fmaf(bf2f(zx[(r + 2) * 32 + h]), kx[2][h], v);
      v = fmaf(bf2f(zx[(r + 3) * 32 + h]), kx[3][h], v);
      float sv, cv;
      __sincosf(v * th[h], &sv, &cv);
      const float p = pw[r];
      sre_acc = fmaf(p, cv, sre_acc);
      sim_acc = fmaf(p, sv, sim_acc);
    }
    __syncthreads();
  }

  // reduce 8 rr-partials per column; den over 64 row-threads
  red[rr][h] = sre_acc;
  red[rr][h + 32] = sim_acc;
  if (tid < 64) dred[tid] = den_acc;
  __syncthreads();
  const int fl = bk * SEG + s;
  if (tid < 64) {
    float t0 = 0.f;
#pragma unroll
    for (int i = 0; i < 8; ++i) t0 += red[i][tid];
    tot[(size_t)fl * 72 + tid] = t0;
  } else if (tid == 64) {
    float t0 = 0.f;
#pragma unroll
    for (int i = 0; i < 64; ++i) t0 += dred[i];
    tot[(size_t)fl * 72 + 64] = t0;
  }
}

// ---------------- exclusive scan of segment totals per chain --------------
__global__ __launch_bounds__(128) void seg_scan(float* __restrict__ tot) {
  const int bk = blockIdx.x, tid = threadIdx.x;
  if (tid >= 65) return;
  float run = 0.f;
#pragma unroll
  for (int s = 0; s < SEG; ++s) {
    const size_t idx = (size_t)(bk * SEG + s) * 72 + tid;
    const float t = tot[idx];
    tot[idx] = run;
    run += t;
  }
}

// ---------------- fused pass 1: scan + norm + head + gate -> g ------------
// Recomputes features, runs the within-segment scan seeded with the
// exclusive segment offset from tot, RMS-normalizes per row, applies the
// 32x32 head matmul (f32 VALU, weights in 64 regs/thread), silu gate, and
// writes compact g [16384][1024] bf16 for GEMM2.
__global__ __launch_bounds__(256) void fuse_pass1(
    const u16* __restrict__ z2x, const u16* __restrict__ z2g,
    const u16* __restrict__ z2s, const float* __restrict__ kern,
    const float* __restrict__ theta, const float* __restrict__ decay,
    const float* __restrict__ anchor, const float* __restrict__ sscale,
    const float* __restrict__ W_re, const float* __restrict__ W_im,
    const float* __restrict__ ns, const float* __restrict__ tot,
    u16* __restrict__ g) {
  __shared__ u16 zx[67 * 32];
  __shared__ u16 zg[67 * 32];
  __shared__ float zs[68];
  __shared__ float f[64 * FST];      // cols 0..31 re, 32..63 im, 64 den
  __shared__ float pw[64];
  __shared__ float kx[4][32], kg[4][32], th[32];
  __shared__ float ks4[4];

  const int tid = threadIdx.x;
  const int bk = blockIdx.x;            // b*32 + k
  const int s = blockIdx.y;
  const int k = bk & 31;
  const int b = bk >> 5;
  const int rr = tid >> 5, h = tid & 31;
  const size_t pbase = (size_t)bk * 4096 * 32;
  const size_t sbase = (size_t)bk * 4096;

  if (tid < 128) {
    const int w_ = tid >> 5, c = tid & 31;
    kx[w_][c] = kern[w_ * ZC + k * 32 + c];
    kg[w_][c] = kern[w_ * ZC + 1024 + k * 32 + c];
  }
  if (tid < 32) th[tid] = theta[k * 32 + tid];
  if (tid < 4) ks4[tid] = kern[tid * ZC + 2048 + k];
  const float slope = (k < KK - AA) ? decay[k] : anchor[k - (KK - AA)];
  const float sp = log1pf(__expf(slope));
  const float sk = sscale[k];
  float wre[32], wim[32];
#pragma unroll
  for (int hp = 0; hp < 32; ++hp) {
    wre[hp] = ns[hp] * W_re[hp * 32 + h];
    wim[hp] = ns[32 + hp] * W_im[hp * 32 + h];
  }
  __syncthreads();

  const int l0 = s * 1024;
  const int fl = bk * SEG + s;
  // seed scan state with the exclusive segment offset
  float run = (tid < 65) ? tot[(size_t)fl * 72 + tid] : 0.f;

#pragma unroll 1
  for (int ch = 0; ch < 16; ++ch) {
    const int r0 = l0 + ch * 64;
    for (int u = tid; u < 268; u += 256) {
      const int row = u >> 2, q = u & 3;
      const int gl = r0 - 3 + row;
      s16x8 vx = {0, 0, 0, 0, 0, 0, 0, 0}, vg = vx;
      if (gl >= 0) {
        vx = *(const s16x8*)(z2x + pbase + (size_t)gl * 32 + q * 8);
        vg = *(const s16x8*)(z2g + pbase + (size_t)gl * 32 + q * 8);
      }
      *(s16x8*)&zx[row * 32 + q * 8] = vx;
      *(s16x8*)&zg[row * 32 + q * 8] = vg;
    }
    if (tid < 67) {
      const int gl = r0 - 3 + tid;
      zs[tid] = (gl >= 0) ? bf2f(z2s[sbase + gl]) : 0.f;
    }
    __syncthreads();
    if (tid < 64) {
      float v = zs[tid] * ks4[0];
      v = fmaf(zs[tid + 1], ks4[1], v);
      v = fmaf(zs[tid + 2], ks4[2], v);
      v = fmaf(zs[tid + 3], ks4[3], v);
      const int l = r0 + tid;
      const float lw = (k < KK - AA) ? (-sp * (float)(LL - 1 - l))
                                     : (-sp * (float)l);
      pw[tid] = __expf(sk * v + lw);
    }
    __syncthreads();
#pragma unroll
    for (int rg = 0; rg < 8; ++rg) {
      const int r = rg * 8 + rr;
      float v = bf2f(zx[r * 32 + h]) * kx[0][h];
      v = fmaf(bf2f(zx[(r + 1) * 32 + h]), kx[1][h], v);
      v = fmaf(bf2f(zx[(r + 2) * 32 + h]), kx[2][h], v);
      v = fmaf(bf2f(zx[(r + 3) * 32 + h]), kx[3][h], v);
      float sv, cv;
      __sincosf(v * th[h], &sv, &cv);
      const float p = pw[r];
      f[r * FST + h] = p * cv;
      f[r * FST + 32 + h] = p * sv;
      if (h == 0) f[r * FST + 64] = p;
    }
    __syncthreads();
    // chunk scan (thread c owns column c; 0..31 re, 32..63 im, 64 den)
    if (tid < 65) {
      float rn = run;
#pragma unroll
      for (int r = 0; r < 64; ++r) {
        rn += f[r * FST + tid];
        f[r * FST + tid] = rn;
      }
      run = rn;
    }
    __syncthreads();
    // normalize + head matmul + gate + write
#pragma unroll
    for (int rg = 0; rg < 8; ++rg) {
      const int r = rg * 8 + rr;
      const float xre = f[r * FST + h], xim = f[r * FST + 32 + h];
      float part = fmaf(xre, xre, xim * xim);
      part += __shfl_xor(part, 1);
      part += __shfl_xor(part, 2);
      part += __shfl_xor(part, 4);
      part += __shfl_xor(part, 8);
      part += __shfl_xor(part, 16);
      const float den = f[r * FST + 64];
      const float inv = 1.0f / fmaxf(den, 1e-4f);
      const float scale =
          inv * rsqrtf(part * inv * inv * (1.0f / 64.0f) + 1e-5f);
      float y = 0.f;
#pragma unroll
      for (int hp = 0; hp < 32; ++hp) {
        y = fmaf(f[r * FST + hp], wre[hp], y);
        y = fmaf(f[r * FST + 32 + hp], wim[hp], y);
      }
      y *= scale;
      float gv = bf2f(zg[r * 32 + h]) * kg[0][h];
      gv = fmaf(bf2f(zg[(r + 1) * 32 + h]), kg[1][h], gv);
      gv = fmaf(bf2f(zg[(r + 2) * 32 + h]), kg[2][h], gv);
      gv = fmaf(bf2f(zg[(r + 3) * 32 + h]), kg[3][h], gv);
      const float sil = gv * (1.0f / (1.0f + __expf(-gv)));
      const int l = r0 + r;
      g[((size_t)(b * 4096 + l)) * 1024 + k * 32 + h] = f2bf(y * sil);
    }
    __syncthreads();
  }
}

// ---------------- launch ----------------
extern "C" void kernel_launch(void* const* d_in, const int* in_sizes, int n_in,
                              void* d_out, int out_size, void* d_ws, size_t ws_size,
                              hipStream_t stream) {
  const float* x      = (const float*)d_in[0];
  const float* W_in   = (const float*)d_in[1];
  const float* kern   = (const float*)d_in[2];
  const float* theta  = (const float*)d_in[3];
  const float* decay  = (const float*)d_in[4];
  const float* anchor = (const float*)d_in[5];
  const float* sscale = (const float*)d_in[6];
  const float* W_re   = (const float*)d_in[7];
  const float* W_im   = (const float*)d_in[8];
  const float* nscale = (const float*)d_in[9];
  const float* W_out  = (const float*)d_in[10];
  float* out = (float*)d_out;

  // workspace layout (~133.4 MiB):
  //   xbf [32 MiB] | z2x [32] | z2g [32] | z2s [1] | g [32] | wbt [4.25]
  //   | tot [144 KiB]
  // wobt (W_out^T) aliases z2x: z2x dead after fuse_pass1.
  char* w = (char*)d_ws;
  u16* xbf   = (u16*)w;
  u16* z2x   = (u16*)(w + 33554432ull);
  u16* z2g   = (u16*)(w + 67108864ull);
  u16* z2s   = (u16*)(w + 100663296ull);
  u16* g     = (u16*)(w + 101711872ull);
  u16* wbt   = (u16*)(w + 135266304ull);
  float* tot = (float*)(w + 139722752ull);
  u16* wobt  = z2x;   // alias

  // 1) casts / transposes
  cast_bf16_kernel<<<dim3(BL * DD / 8 / 256), 256, 0, stream>>>(x, xbf, BL * DD);
  transpose_cast_kernel<<<dim3(32, 68), 256, 0, stream>>>(W_in, wbt, DD, ZC, NPAD);

  // 2a) score cols -> z2s
  score_gemm<<<dim3(BL / 128), 256, 0, stream>>>(xbf, wbt, z2s);

  // 2b) GEMM1: z = x @ W_in[:, :2048], written head-blocked into z2x/z2g.
  // grid = 64x8 = 512 blocks = 2 clean dispatch rounds.
  gemm256_8ph<2><<<dim3(BL / 256, 8), 512, 0, stream>>>(
      xbf, wbt, z2x, z2g, DD, DD, 0, DD, 2048);

  // 3) fused pipeline, deterministic 3-launch scan (no inter-block waits)
  fuse_pass0<<<dim3(BB * KK, SEG), 256, 0, stream>>>(
      z2x, z2s, kern, theta, decay, anchor, sscale, tot);
  seg_scan<<<dim3(BB * KK), 128, 0, stream>>>(tot);
  fuse_pass1<<<dim3(BB * KK, SEG), 256, 0, stream>>>(
      z2x, z2g, z2s, kern, theta, decay, anchor, sscale,
      W_re, W_im, nscale, tot, g);

  // 4) W_out^T (into dead z2x region), then GEMM2: out = g @ W_out
  transpose_cast_kernel<<<dim3(32, 32), 256, 0, stream>>>(W_out, wobt, DI, DD, DD);
  gemm256_8ph<0><<<dim3(BL / 256, DD / 256), 512, 0, stream>>>(
      g, wobt, out, nullptr, DI, DD, DD, DI, DD);
}

// Round 7
// 363.858 us; speedup vs baseline: 1.1355x; 1.1355x over previous
//
#include <hip/hip_runtime.h>
#include <hip/hip_bf16.h>
#include <math.h>

// ---------------- static problem config ----------------
#define BB 4
#define LL 4096
#define DD 1024
#define KK 32
#define HH 32
#define AA 4
#define CKK 4
#define DI 1024
#define ZC 2080            // 2*DI + KK
#define FLATC 1024         // K*H
#define BL (BB * LL)       // 16384
#define ZLD 2080           // z row stride (bf16)
#define NPAD 2176          // W_in^T padded rows (17*128)

// scan config: chunk == conv block == 32 rows
#define CCH 32
#define NCHK (LL / CCH)    // 128 chunks per b

// norm_head LDS strides (skewed to break lq-stride-128 bank conflicts)
#define GLD 1136           // zw row stride in u16 : col = o + (o>>7)*16
#define KLD 1080           // skern row stride in f32: col = o + (o>>7)*8

typedef unsigned short u16;
typedef __attribute__((ext_vector_type(8))) short s16x8;
typedef __attribute__((ext_vector_type(4))) float f32x4;

__device__ __forceinline__ u16 f2bf(float f) {
  union { float f; unsigned int u; } v; v.f = f;
  unsigned int r = (v.u + 0x7FFFu + ((v.u >> 16) & 1u)) >> 16;
  return (u16)r;
}
__device__ __forceinline__ float bf2f(u16 u) {
  union { unsigned int i; float f; } x; x.i = ((unsigned int)u) << 16; return x.f;
}
__device__ __forceinline__ void gl_lds16(const void* g, void* l) {
  __builtin_amdgcn_global_load_lds(
      (const __attribute__((address_space(1))) unsigned int*)g,
      (__attribute__((address_space(3))) unsigned int*)l, 16, 0, 0);
}

// ---------------- cast f32 -> bf16 (x) ----------------
__global__ __launch_bounds__(256) void cast_bf16_kernel(
    const float* __restrict__ src, u16* __restrict__ dst, int n) {
  const int i = (blockIdx.x * 256 + threadIdx.x) * 8;
  if (i >= n) return;
  float4 a = *(const float4*)(src + i);
  float4 b = *(const float4*)(src + i + 4);
  s16x8 v;
  v[0] = (short)f2bf(a.x); v[1] = (short)f2bf(a.y);
  v[2] = (short)f2bf(a.z); v[3] = (short)f2bf(a.w);
  v[4] = (short)f2bf(b.x); v[5] = (short)f2bf(b.y);
  v[6] = (short)f2bf(b.z); v[7] = (short)f2bf(b.w);
  *(s16x8*)(dst + i) = v;
}

// ---------------- transpose + cast: src[R][C] f32 -> dst[Cpad][R] bf16 ----
__global__ __launch_bounds__(256) void transpose_cast_kernel(
    const float* __restrict__ src, u16* __restrict__ dst,
    int R, int C, int Cpad) {
  __shared__ float t[32][33];
  const int tid = threadIdx.x;
  const int r0 = blockIdx.x * 32, c0 = blockIdx.y * 32;
  const int lr = tid >> 5, lc = tid & 31;
#pragma unroll
  for (int i = 0; i < 4; ++i) {
    const int r = r0 + i * 8 + lr, c = c0 + lc;
    float v = 0.f;
    if (r < R && c < C) v = src[(size_t)r * C + c];
    t[lc][i * 8 + lr] = v;
  }
  __syncthreads();
#pragma unroll
  for (int i = 0; i < 4; ++i) {
    const int dr = c0 + i * 8 + lr;   // row in dst = col in src
    const int dc = r0 + lc;           // col in dst = row in src
    if (dr < Cpad && dc < R) dst[(size_t)dr * R + dc] = f2bf(t[i * 8 + lr][lc]);
  }
}

// ---------------- 256x256 8-phase bf16 MFMA GEMM (T1+T2+T3+T4+T5) --------
// C[M,N] = A[M,K] * Bt[N,K]^T.  512 threads = 8 waves (2M x 4N), per-wave
// output 128x64 (8x4 fragments of 16x16), BK=64, NT = K/64 tiles (even).
//
// LDS 128KB: 8 half-regions of 16KB (128 rows x 64 cols bf16, row-major).
// 3-bit XOR swizzle: elem_col ^= (row&7)<<3; conflict-free (verified:
// SQ_LDS_BANK_CONFLICT 7.08M -> 0). global_load_lds writes LINEAR dest,
// swizzle applied by pre-swizzling the GLOBAL source column (rule #21).
// Counted vmcnt(6) at phases 3/7 only; raw s_barrier (no vmcnt(0) drain).
#define FENCE() asm volatile("" ::: "memory")
#define SBAR() do { FENCE(); __builtin_amdgcn_s_barrier(); FENCE(); } while (0)
#define VMCNT6() asm volatile("s_waitcnt vmcnt(6)" ::: "memory")

#define RA(s, h) (((s) * 2 + (h)) * 8192)
#define RB(s, h) (32768 + ((s) * 2 + (h)) * 8192)

template <int OUT_BF16>
__global__ __launch_bounds__(512, 2) void gemm256_8ph(
    const u16* __restrict__ A, const u16* __restrict__ Bt, void* __restrict__ C,
    int lda, int ldb, int ldc, int Kd, int Ncols) {
  __shared__ u16 lds[65536];   // 128 KiB
  const int tid = threadIdx.x;
  const int lane = tid & 63, wv = tid >> 6;
  const int wm = wv >> 2, wn = wv & 3;       // 2M x 4N wave grid
  const int lm = lane & 15, lq = lane >> 4;
  const int bm = blockIdx.x * 256, bn = blockIdx.y * 256;
  const int NT = Kd >> 6;                    // K tiles (even)
  const int NT2 = NT >> 1;

  const int rofs = wv * 8 + (lane >> 3);                 // region row
  const int cel = ((lane & 7) ^ (lane >> 3)) * 8;        // col elems, swz

  auto stageH = [&](const u16* __restrict__ G, int rowBase, int ld, int kt,
                    int regU16) {
    const u16* g0 = G + (size_t)(rowBase + rofs) * ld + (kt << 6) + cel;
    gl_lds16(g0, &lds[regU16 + wv * 512]);
    const u16* g1 = G + (size_t)(rowBase + 64 + rofs) * ld + (kt << 6) + cel;
    gl_lds16(g1, &lds[regU16 + 4096 + wv * 512]);
  };

  s16x8 Af[4][2], Bf[4][2];
  f32x4 acc[8][4];
  const f32x4 z4 = {0.f, 0.f, 0.f, 0.f};
#pragma unroll
  for (int i = 0; i < 8; ++i)
#pragma unroll
    for (int j = 0; j < 4; ++j) acc[i][j] = z4;

  const int xorw = (lm & 7) << 3;   // read-side swizzle XOR in u16 units

#define DSA(s, mh)                                                          \
  _Pragma("unroll") for (int f = 0; f < 4; ++f)                             \
  _Pragma("unroll") for (int ks = 0; ks < 2; ++ks)                          \
    Af[f][ks] = *(const s16x8*)&lds[RA(s, wm) +                             \
      (((((mh) * 4 + f) * 16 + lm) * 64 + ((ks * 32 + lq * 8) ^ xorw)))];

#define DSB(s)                                                              \
  _Pragma("unroll") for (int f = 0; f < 4; ++f)                             \
  _Pragma("unroll") for (int ks = 0; ks < 2; ++ks)                          \
    Bf[f][ks] = *(const s16x8*)&lds[RB(s, wn >> 1) +                        \
      ((((wn & 1) * 64 + f * 16 + lm) * 64 + ((ks * 32 + lq * 8) ^ xorw)))];

#define QUAD(mh, nh)                                                        \
  do {                                                                      \
    __builtin_amdgcn_s_setprio(1);                                          \
    _Pragma("unroll") for (int f = 0; f < 4; ++f)                           \
    _Pragma("unroll") for (int n = 0; n < 2; ++n)                           \
    _Pragma("unroll") for (int ks = 0; ks < 2; ++ks)                        \
      acc[(mh) * 4 + f][(nh) * 2 + n] =                                     \
          __builtin_amdgcn_mfma_f32_16x16x32_bf16(                          \
              Af[f][ks], Bf[(nh) * 2 + n][ks],                              \
              acc[(mh) * 4 + f][(nh) * 2 + n], 0, 0, 0);                    \
    __builtin_amdgcn_s_setprio(0);                                          \
  } while (0)

  // ---- prologue: 7 halves (t0 full + t1 B0,B1,A0); t1A1 comes at p0 ----
  stageH(A, bm, lda, 0, RA(0, 0));
  stageH(A, bm + 128, lda, 0, RA(0, 1));
  stageH(Bt, bn, ldb, 0, RB(0, 0));
  stageH(Bt, bn + 128, ldb, 0, RB(0, 1));
  stageH(Bt, bn, ldb, 1, RB(1, 0));
  stageH(Bt, bn + 128, ldb, 1, RB(1, 1));
  stageH(A, bm, lda, 1, RA(1, 0));
  VMCNT6();        // first 4 halves (tile 0) landed
  SBAR();

#pragma unroll 1
  for (int t = 0; t < NT2; ++t) {
    const int T2 = 2 * t + 2, T3 = 2 * t + 3;
    // -------- tile 2t from slot 0 --------
    DSA(0, 0); DSB(0);
    stageH(A, bm + 128, lda, 2 * t + 1, RA(1, 1));   // s1A1 of tile 2t+1
    SBAR();
    QUAD(0, 0);
    SBAR();
    if (T2 < NT) stageH(Bt, bn, ldb, T2, RB(0, 0));
    SBAR();
    QUAD(0, 1);
    SBAR();
    DSA(0, 1);
    if (T2 < NT) stageH(Bt, bn + 128, ldb, T2, RB(0, 1));
    SBAR();
    QUAD(1, 0);
    SBAR();
    if (T2 < NT) stageH(A, bm, lda, T2, RA(0, 0));
    SBAR();
    QUAD(1, 1);
    VMCNT6();      // slot1 (tile 2t+1) fully landed before p4 reads
    SBAR();
    // -------- tile 2t+1 from slot 1 --------
    DSA(1, 0); DSB(1);
    if (T2 < NT) stageH(A, bm + 128, lda, T2, RA(0, 1));
    SBAR();
    QUAD(0, 0);
    SBAR();
    if (T3 < NT) stageH(Bt, bn, ldb, T3, RB(1, 0));
    SBAR();
    QUAD(0, 1);
    SBAR();
    DSA(1, 1);
    if (T3 < NT) stageH(Bt, bn + 128, ldb, T3, RB(1, 1));
    SBAR();
    QUAD(1, 0);
    SBAR();
    if (T3 < NT) stageH(A, bm, lda, T3, RA(1, 0));
    SBAR();
    QUAD(1, 1);
    VMCNT6();      // slot0 (tile 2t+2) fully landed before next p0 reads
    SBAR();
  }

  // epilogue: D col = lm, row = lq*4 + r within each 16x16 fragment
#pragma unroll
  for (int f = 0; f < 8; ++f) {
#pragma unroll
    for (int n = 0; n < 4; ++n) {
#pragma unroll
      for (int r = 0; r < 4; ++r) {
        const int row = bm + wm * 128 + f * 16 + lq * 4 + r;
        const int col = bn + wn * 64 + n * 16 + lm;
        if (col < Ncols) {
          if (OUT_BF16)
            ((u16*)C)[(size_t)row * ldc + col] = f2bf(acc[f][n][r]);
          else
            ((float*)C)[(size_t)row * ldc + col] = acc[f][n][r];
        }
      }
    }
  }
#undef DSA
#undef DSB
#undef QUAD
}

// ---------------- score GEMM: z[:,2048:2080] = x @ W_in[:,2048:2080] -----
__global__ __launch_bounds__(256) void score_gemm(
    const u16* __restrict__ A, const u16* __restrict__ Bt,
    u16* __restrict__ z) {
  __shared__ u16 As[8192];   // 16 units x 512 elems (128 rows x 64 k)
  __shared__ u16 Bs[2048];   // 4 units  (32 rows x 64 k)
  const int tid = threadIdx.x;
  const int lane = tid & 63, wv = tid >> 6;
  const int lm = lane & 15, lq = lane >> 4;
  const int bm = blockIdx.x * 128;

  const f32x4 z4 = {0.f, 0.f, 0.f, 0.f};
  f32x4 acc[2][2];
#pragma unroll
  for (int i = 0; i < 2; ++i)
#pragma unroll
    for (int j = 0; j < 2; ++j) acc[i][j] = z4;

  for (int k0 = 0; k0 < DD; k0 += 64) {
    __syncthreads();
#pragma unroll
    for (int t = 0; t < 5; ++t) {
      const int idx = wv * 5 + t;            // 0..19
      if (idx < 16) {                        // A unit (mt, kt)
        const int mt = idx >> 1, kt = idx & 1;
        const u16* g = A + (size_t)(bm + mt * 16 + lm) * DD + k0 + kt * 32 + lq * 8;
        gl_lds16(g, &As[idx * 512]);
      } else {                               // B unit (nt, kt)
        const int bidx = idx - 16;
        const int nt = bidx >> 1, kt = bidx & 1;
        const u16* g = Bt + (size_t)(2048 + nt * 16 + lm) * DD + k0 + kt * 32 + lq * 8;
        gl_lds16(g, &Bs[bidx * 512]);
      }
    }
    __syncthreads();
#pragma unroll
    for (int kt = 0; kt < 2; ++kt) {
      s16x8 af[2], bfb[2];
#pragma unroll
      for (int i = 0; i < 2; ++i) {
        const int mt = wv * 2 + i;
        af[i] = *(const s16x8*)&As[(mt * 2 + kt) * 512 + lane * 8];
        bfb[i] = *(const s16x8*)&Bs[(i * 2 + kt) * 512 + lane * 8];
      }
#pragma unroll
      for (int i = 0; i < 2; ++i)
#pragma unroll
        for (int j = 0; j < 2; ++j)
          acc[i][j] = __builtin_amdgcn_mfma_f32_16x16x32_bf16(af[i], bfb[j], acc[i][j], 0, 0, 0);
    }
  }
#pragma unroll
  for (int i = 0; i < 2; ++i)
#pragma unroll
    for (int j = 0; j < 2; ++j)
#pragma unroll
      for (int r = 0; r < 4; ++r) {
        const int row = bm + wv * 32 + i * 16 + lq * 4 + r;
        const int col = 2048 + j * 16 + lm;
        z[(size_t)row * ZLD + col] = f2bf(acc[i][j][r]);
      }
}

// ---------------- conv + p_w + features + chunk-local cumsum --------------
// One block = one 32-row chunk. Phase C stages each 35-row x 256-col z
// panel into LDS with s16x8 VECTOR loads (16B/lane, G13) instead of the
// previous 128 scalar 2B loads per thread, then reads taps from LDS with
// a rolling register history. Chunk totals go to part[chunk].
__global__ __launch_bounds__(256) void conv_feat_scan(
    const u16* __restrict__ z, const float* __restrict__ kern,
    const float* __restrict__ theta, const float* __restrict__ decay,
    const float* __restrict__ anchor, const float* __restrict__ sscale,
    float* __restrict__ merged, float* __restrict__ part) {
  __shared__ float pbuf[CCH][KK];   // raw p_w per (row, head)
  __shared__ u16 zt[35 * 256];      // staged z panel (17.5 KB)
  const int tid = threadIdx.x;
  const int r0 = blockIdx.x * CCH;           // global row base
  const bool first = ((r0 & (LL - 1)) == 0);
  const int chunk = blockIdx.x;              // global chunk id

  // phase A: p_w for 32 rows x 32 heads (4 items/thread)
#pragma unroll
  for (int q = 0; q < 4; ++q) {
    const int item = q * 256 + tid;
    const int row = item >> 5, k = item & 31;
    float v = 0.f;
#pragma unroll
    for (int w = 0; w < CKK; ++w) {
      const int g = row + w;                 // offset from r0-3
      float zv = 0.f;
      if (!(first && g < 3))
        zv = bf2f(z[(size_t)(r0 - 3 + g) * ZLD + 2048 + k]);
      v = fmaf(zv, kern[w * ZC + 2048 + k], v);
    }
    const int l = (r0 + row) & (LL - 1);
    const float slope = (k < KK - AA) ? decay[k] : anchor[k - (KK - AA)];
    const float sp = log1pf(__expf(slope));
    const float lw = (k < KK - AA) ? (-sp * (float)(LL - 1 - l)) : (-sp * (float)l);
    pbuf[row][k] = __expf(sscale[k] * v + lw);
  }
  __syncthreads();

  // phase B: den chunk-local cumsum (32 threads; LDS reads conflict-free)
  if (tid < KK) {
    float run = 0.f;
#pragma unroll
    for (int row = 0; row < CCH; ++row) {
      run += pbuf[row][tid];
      merged[(size_t)(r0 + row) * ZC + tid] = run;
    }
    part[(size_t)chunk * ZC + tid] = run;
  }

  // phase C: features + chunk-local cumsum. Per it: stage 35x256 panel
  // (vector loads), then rolling 4-tap conv from LDS.
#pragma unroll 1
  for (int it = 0; it < 4; ++it) {
    __syncthreads();   // protect zt reuse (and pbuf/phase-B on it==0)
    for (int u = tid; u < 35 * 32; u += 256) {
      const int row = u >> 5, q8 = (u & 31) * 8;
      s16x8 v = {0, 0, 0, 0, 0, 0, 0, 0};
      if (!(first && row < 3))
        v = *(const s16x8*)(z + (size_t)(r0 - 3 + row) * ZLD + it * 256 + q8);
      *(s16x8*)&zt[row * 256 + q8] = v;
    }
    __syncthreads();

    const int c = it * 256 + tid;            // 0..1023
    const float kw0 = kern[0 * ZC + c], kw1 = kern[1 * ZC + c];
    const float kw2 = kern[2 * ZC + c], kw3 = kern[3 * ZC + c];
    const float th = theta[c];
    const int head = c >> 5;
    float h0 = bf2f(zt[0 * 256 + tid]);
    float h1 = bf2f(zt[1 * 256 + tid]);
    float h2 = bf2f(zt[2 * 256 + tid]);
    float sre = 0.f, sim = 0.f;
#pragma unroll 4
    for (int row = 0; row < CCH; ++row) {
      const float h3 = bf2f(zt[(row + 3) * 256 + tid]);
      float v = h0 * kw0;
      v = fmaf(h1, kw1, v);
      v = fmaf(h2, kw2, v);
      v = fmaf(h3, kw3, v);
      h0 = h1; h1 = h2; h2 = h3;
      const float phi = v * th;
      float sv, cv;
      __sincosf(phi, &sv, &cv);
      const float p = pbuf[row][head];
      sre = fmaf(p, cv, sre);
      sim = fmaf(p, sv, sim);
      float* mrow = merged + (size_t)(r0 + row) * ZC;
      mrow[KK + c] = sre;
      mrow[KK + FLATC + c] = sim;
    }
    part[(size_t)chunk * ZC + KK + c] = sre;
    part[(size_t)chunk * ZC + KK + FLATC + c] = sim;
  }
}

// ---------------- exclusive scan of chunk totals (128 chunks per b) -------
__global__ __launch_bounds__(256) void scan_offsets_kernel(float* __restrict__ part) {
  const int c = blockIdx.x * 256 + threadIdx.x;
  const int b = blockIdx.z;
  if (c >= ZC) return;
  float run = 0.f;
#pragma unroll 8
  for (int i = 0; i < NCHK; ++i) {
    const size_t idx = ((size_t)b * NCHK + i) * ZC + c;
    const float t = part[idx];
    part[idx] = run;
    run += t;
  }
}

// ---------------- fold norm_scale into head weights (bf16) ----------------
__global__ __launch_bounds__(256) void wprime_kernel(
    const float* __restrict__ W_re, const float* __restrict__ W_im,
    const float* __restrict__ ns, u16* __restrict__ wp) {
  const int i = blockIdx.x * 256 + threadIdx.x;   // 0..2047
  if (i < 1024) wp[i] = f2bf(ns[i >> 5] * W_re[i]);
  else {
    const int j = i - 1024;
    wp[i] = f2bf(ns[32 + (j >> 5)] * W_im[j]);
  }
}

// ---------------- norm_head via MFMA ----------------
// Block = 8 bl rows (4 waves x 2 rows). merged holds CHUNK-LOCAL cumsum;
// the global prefix is chunk-local + part[chunk] (exclusive offsets),
// added at load time (den and re/im). Per (bl,k) row: scale from raw row
// sums, y = [re;im]*scale @ [Wre';Wim'] via 16x16x32 bf16 MFMA, g = y*gate
// written bf16 in-place into merged row head (den read before any write).
__global__ __launch_bounds__(256) void norm_head_mfma(
    float* merged, const u16* __restrict__ z, const float* __restrict__ kern,
    const u16* __restrict__ wp, const float* __restrict__ part) {
  __shared__ u16 zw[11 * GLD];       // skewed gate-z tile
  __shared__ float skern[4 * KLD];   // skewed gate conv weights
  const int tid = threadIdx.x;
  const int r0 = blockIdx.x * 8;
  const bool first = ((r0 & (LL - 1)) == 0);
  const int lane = tid & 63, wv = tid >> 6;
  const int lm = lane & 15, lq = lane >> 4;
  // chunk offsets row for this block (8 rows always within one 32-row chunk)
  const float* po = part + (size_t)(blockIdx.x >> 2) * ZC;

  // stage z gate cols (1024..2047), rows r0-3 .. r0+7, with skew
  for (int idx = tid; idx < 11 * 128; idx += 256) {
    const int i = idx >> 7, c8 = idx & 127;
    s16x8 v = {0, 0, 0, 0, 0, 0, 0, 0};
    if (!(first && i < 3))
      v = *(const s16x8*)(z + (size_t)(r0 - 3 + i) * ZLD + 1024 + c8 * 8);
    *(s16x8*)&zw[i * GLD + c8 * 8 + (c8 >> 4) * 16] = v;
  }
  // stage gate conv weights (f32) with skew
  for (int idx = tid; idx < 4 * 256; idx += 256) {
    const int w = idx >> 8, c4 = idx & 255;
    float4 v = *(const float4*)(kern + w * ZC + 1024 + c4 * 4);
    *(float4*)&skern[w * KLD + c4 * 4 + (c4 >> 5) * 8] = v;
  }

  // B fragments (same for all rows): lane(lm,lq) holds W'[lq*8+j][nt*16+lm]
  s16x8 bre[2], bim[2];
#pragma unroll
  for (int nt = 0; nt < 2; ++nt)
#pragma unroll
    for (int jj = 0; jj < 8; ++jj) {
      bre[nt][jj] = (short)wp[(lq * 8 + jj) * 32 + nt * 16 + lm];
      bim[nt][jj] = (short)wp[1024 + (lq * 8 + jj) * 32 + nt * 16 + lm];
    }
  __syncthreads();

  const f32x4 z4 = {0.f, 0.f, 0.f, 0.f};
#pragma unroll 1
  for (int rr2 = 0; rr2 < 2; ++rr2) {
    const int rr = wv * 2 + rr2;          // 0..7 within block
    const int bl = r0 + rr;
    float* row = merged + (size_t)bl * ZC;
    // den for BOTH k-halves, before any write to this row (+ chunk offset)
    const float den0 = row[lm] + po[lm];
    const float den1 = row[16 + lm] + po[16 + lm];

#pragma unroll
    for (int khalf = 0; khalf < 2; ++khalf) {
      // A loads: re/im for (bl, k = khalf*16+lm), hp = lq*8..lq*8+7
      const int co = KK + (khalf * 16 + lm) * 32 + lq * 8;
      const float* rp = row + co;
      const float* pp = po + co;
      float4 ra = *(const float4*)rp;
      float4 rb = *(const float4*)(rp + 4);
      float4 ia = *(const float4*)(rp + FLATC);
      float4 ib = *(const float4*)(rp + FLATC + 4);
      float4 qa = *(const float4*)pp;
      float4 qb = *(const float4*)(pp + 4);
      float4 ja = *(const float4*)(pp + FLATC);
      float4 jb = *(const float4*)(pp + FLATC + 4);
      ra.x += qa.x; ra.y += qa.y; ra.z += qa.z; ra.w += qa.w;
      rb.x += qb.x; rb.y += qb.y; rb.z += qb.z; rb.w += qb.w;
      ia.x += ja.x; ia.y += ja.y; ia.z += ja.z; ia.w += ja.w;
      ib.x += jb.x; ib.y += jb.y; ib.z += jb.z; ib.w += jb.w;

      float ssq = ra.x * ra.x + ra.y * ra.y + ra.z * ra.z + ra.w * ra.w +
                  rb.x * rb.x + rb.y * rb.y + rb.z * rb.z + rb.w * rb.w +
                  ia.x * ia.x + ia.y * ia.y + ia.z * ia.z + ia.w * ia.w +
                  ib.x * ib.x + ib.y * ib.y + ib.z * ib.z + ib.w * ib.w;
      ssq += __shfl_xor(ssq, 16);
      ssq += __shfl_xor(ssq, 32);
      const float den = khalf ? den1 : den0;
      const float inv = 1.0f / fmaxf(den, 1e-4f);
      const float scale = inv * rsqrtf(ssq * inv * inv * (1.0f / 64.0f) + 1e-5f);

      s16x8 afr, afi;
      afr[0] = (short)f2bf(ra.x * scale); afr[1] = (short)f2bf(ra.y * scale);
      afr[2] = (short)f2bf(ra.z * scale); afr[3] = (short)f2bf(ra.w * scale);
      afr[4] = (short)f2bf(rb.x * scale); afr[5] = (short)f2bf(rb.y * scale);
      afr[6] = (short)f2bf(rb.z * scale); afr[7] = (short)f2bf(rb.w * scale);
      afi[0] = (short)f2bf(ia.x * scale); afi[1] = (short)f2bf(ia.y * scale);
      afi[2] = (short)f2bf(ia.z * scale); afi[3] = (short)f2bf(ia.w * scale);
      afi[4] = (short)f2bf(ib.x * scale); afi[5] = (short)f2bf(ib.y * scale);
      afi[6] = (short)f2bf(ib.z * scale); afi[7] = (short)f2bf(ib.w * scale);

      f32x4 acc[2];
#pragma unroll
      for (int nt = 0; nt < 2; ++nt) {
        acc[nt] = __builtin_amdgcn_mfma_f32_16x16x32_bf16(afr, bre[nt], z4, 0, 0, 0);
        acc[nt] = __builtin_amdgcn_mfma_f32_16x16x32_bf16(afi, bim[nt], acc[nt], 0, 0, 0);
      }

      // epilogue: D row = lq*4+r (k offset), col = lm (h offset)
      u16* grow = (u16*)row;
#pragma unroll
      for (int nt = 0; nt < 2; ++nt) {
#pragma unroll
        for (int r = 0; r < 4; ++r) {
          const int k = khalf * 16 + lq * 4 + r;
          const int o = k * 32 + nt * 16 + lm;
          const int sk = o + (o >> 7) * 8;    // skern skew
          const int sz = o + (o >> 7) * 16;   // zw skew
          float gv = bf2f(zw[(rr + 0) * GLD + sz]) * skern[0 * KLD + sk];
          gv = fmaf(bf2f(zw[(rr + 1) * GLD + sz]), skern[1 * KLD + sk], gv);
          gv = fmaf(bf2f(zw[(rr + 2) * GLD + sz]), skern[2 * KLD + sk], gv);
          gv = fmaf(bf2f(zw[(rr + 3) * GLD + sz]), skern[3 * KLD + sk], gv);
          const float sil = gv * (1.0f / (1.0f + __expf(-gv)));
          grow[o] = f2bf(acc[nt][r] * sil);
        }
      }
    }
  }
}

// ---------------- launch ----------------
extern "C" void kernel_launch(void* const* d_in, const int* in_sizes, int n_in,
                              void* d_out, int out_size, void* d_ws, size_t ws_size,
                              hipStream_t stream) {
  const float* x      = (const float*)d_in[0];
  const float* W_in   = (const float*)d_in[1];
  const float* kern   = (const float*)d_in[2];
  const float* theta  = (const float*)d_in[3];
  const float* decay  = (const float*)d_in[4];
  const float* anchor = (const float*)d_in[5];
  const float* sscale = (const float*)d_in[6];
  const float* W_re   = (const float*)d_in[7];
  const float* W_im   = (const float*)d_in[8];
  const float* nscale = (const float*)d_in[9];
  const float* W_out  = (const float*)d_in[10];
  float* out = (float*)d_out;

  // workspace layout (~199.3 MiB used; fits the proven budget):
  //   merged [136.31 MB] | zbf [68.16 MB] | wp [4 KB] | wbt [4.26 MB] | slack
  // part (512 x 2080 f32 = 4.26 MB) ALIASES wbt: wbt dead after GEMM1+
  // score_gemm, part written by conv_feat_scan afterwards (stream-ordered).
  char* w = (char*)d_ws;
  float* merged = (float*)w;
  u16* xbf = (u16*)w;                                  // alias: dead once gemm1 done
  u16* zbf = (u16*)(w + (size_t)BL * ZC * 4);
  u16* wobt = zbf;                                     // alias: written after norm_head
  u16* wp = (u16*)(w + (size_t)BL * ZC * 4 + (size_t)BL * ZLD * 2);
  u16* wbt = wp + 2048;
  float* part = (float*)wbt;                           // alias (see above)

  // 1) casts / transposes / weight fold
  cast_bf16_kernel<<<dim3(BL * DD / 8 / 256), 256, 0, stream>>>(x, xbf, BL * DD);
  transpose_cast_kernel<<<dim3(32, 68), 256, 0, stream>>>(W_in, wbt, DD, ZC, NPAD);
  wprime_kernel<<<dim3(8), 256, 0, stream>>>(W_re, W_im, nscale, wp);

  // 2a) score cols 2048..2079 of z (tiny GEMM, removes the 9th col tile)
  score_gemm<<<dim3(BL / 128), 256, 0, stream>>>(xbf, wbt, zbf);

  // 2b) GEMM1 main: z[:, :2048] = x @ W_in[:, :2048]. grid = 64x8 = 512
  // blocks = exactly 2 clean dispatch rounds at 1 block/CU.
  gemm256_8ph<1><<<dim3(BL / 256, 8), 512, 0, stream>>>(
      xbf, wbt, zbf, DD, DD, ZLD, DD, ZC);

  // 3) conv + p_w + features + chunk-local cumsum -> merged, part
  conv_feat_scan<<<dim3(BL / CCH), 256, 0, stream>>>(
      zbf, kern, theta, decay, anchor, sscale, merged, part);

  // 4) exclusive scan of chunk totals (in-place on part)
  {
    dim3 grid2((ZC + 255) / 256, 1, BB);
    scan_offsets_kernel<<<grid2, 256, 0, stream>>>(part);
  }

  // 5) normalize + RMS + head matmuls (MFMA) + gate -> g (bf16, in-place)
  norm_head_mfma<<<dim3(BL / 8), 256, 0, stream>>>(merged, zbf, kern, wp, part);

  // 6) W_out^T (into dead z region), then GEMM2: out = g @ W_out (f32 out)
  transpose_cast_kernel<<<dim3(32, 32), 256, 0, stream>>>(W_out, wobt, DI, DD, DD);
  gemm256_8ph<0><<<dim3(BL / 256, DD / 128 / 2), 512, 0, stream>>>(
      (const u16*)merged, wobt, out, 2 * ZC, DI, DD, DI, DD);
}

// Round 8
// 361.036 us; speedup vs baseline: 1.1444x; 1.0078x over previous
//
#include <hip/hip_runtime.h>
#include <hip/hip_bf16.h>
#include <math.h>

// ---------------- static problem config ----------------
#define BB 4
#define LL 4096
#define DD 1024
#define KK 32
#define HH 32
#define AA 4
#define CKK 4
#define DI 1024
#define ZC 2080            // 2*DI + KK
#define FLATC 1024         // K*H
#define BL (BB * LL)       // 16384
#define ZLD 2080           // z row stride (bf16)
#define NPAD 2176          // W_in^T padded rows (17*128)

// scan config: chunk == conv block == 32 rows
#define CCH 32
#define NCHK (LL / CCH)    // 128 chunks per b

// norm_head LDS strides (skewed to break lq-stride-128 bank conflicts)
#define GLD 1136           // zw row stride in u16 : col = o + (o>>7)*16
#define KLD 1080           // skern row stride in f32: col = o + (o>>7)*8
#define SGLD 1080          // sgf (silu-gate f32) row stride: col = o + (o>>7)*8

typedef unsigned short u16;
typedef __attribute__((ext_vector_type(8))) short s16x8;
typedef __attribute__((ext_vector_type(4))) float f32x4;

__device__ __forceinline__ u16 f2bf(float f) {
  union { float f; unsigned int u; } v; v.f = f;
  unsigned int r = (v.u + 0x7FFFu + ((v.u >> 16) & 1u)) >> 16;
  return (u16)r;
}
__device__ __forceinline__ float bf2f(u16 u) {
  union { unsigned int i; float f; } x; x.i = ((unsigned int)u) << 16; return x.f;
}
__device__ __forceinline__ void gl_lds16(const void* g, void* l) {
  __builtin_amdgcn_global_load_lds(
      (const __attribute__((address_space(1))) unsigned int*)g,
      (__attribute__((address_space(3))) unsigned int*)l, 16, 0, 0);
}

// ---------------- cast f32 -> bf16 (x) ----------------
__global__ __launch_bounds__(256) void cast_bf16_kernel(
    const float* __restrict__ src, u16* __restrict__ dst, int n) {
  const int i = (blockIdx.x * 256 + threadIdx.x) * 8;
  if (i >= n) return;
  float4 a = *(const float4*)(src + i);
  float4 b = *(const float4*)(src + i + 4);
  s16x8 v;
  v[0] = (short)f2bf(a.x); v[1] = (short)f2bf(a.y);
  v[2] = (short)f2bf(a.z); v[3] = (short)f2bf(a.w);
  v[4] = (short)f2bf(b.x); v[5] = (short)f2bf(b.y);
  v[6] = (short)f2bf(b.z); v[7] = (short)f2bf(b.w);
  *(s16x8*)(dst + i) = v;
}

// ---------------- transpose + cast: src[R][C] f32 -> dst[Cpad][R] bf16 ----
__global__ __launch_bounds__(256) void transpose_cast_kernel(
    const float* __restrict__ src, u16* __restrict__ dst,
    int R, int C, int Cpad) {
  __shared__ float t[32][33];
  const int tid = threadIdx.x;
  const int r0 = blockIdx.x * 32, c0 = blockIdx.y * 32;
  const int lr = tid >> 5, lc = tid & 31;
#pragma unroll
  for (int i = 0; i < 4; ++i) {
    const int r = r0 + i * 8 + lr, c = c0 + lc;
    float v = 0.f;
    if (r < R && c < C) v = src[(size_t)r * C + c];
    t[lc][i * 8 + lr] = v;
  }
  __syncthreads();
#pragma unroll
  for (int i = 0; i < 4; ++i) {
    const int dr = c0 + i * 8 + lr;   // row in dst = col in src
    const int dc = r0 + lc;           // col in dst = row in src
    if (dr < Cpad && dc < R) dst[(size_t)dr * R + dc] = f2bf(t[i * 8 + lr][lc]);
  }
}

// ---------------- 256x256 8-phase bf16 MFMA GEMM (T1+T2+T3+T4+T5) --------
// C[M,N] = A[M,K] * Bt[N,K]^T.  512 threads = 8 waves (2M x 4N), per-wave
// output 128x64 (8x4 fragments of 16x16), BK=64, NT = K/64 tiles (even).
//
// LDS 128KB: 8 half-regions of 16KB (128 rows x 64 cols bf16, row-major).
// 3-bit XOR swizzle: elem_col ^= (row&7)<<3; conflict-free (verified:
// SQ_LDS_BANK_CONFLICT 7.08M -> 0). global_load_lds writes LINEAR dest,
// swizzle applied by pre-swizzling the GLOBAL source column (rule #21).
// Counted vmcnt(6) at phases 3/7 only; raw s_barrier (no vmcnt(0) drain).
#define FENCE() asm volatile("" ::: "memory")
#define SBAR() do { FENCE(); __builtin_amdgcn_s_barrier(); FENCE(); } while (0)
#define VMCNT6() asm volatile("s_waitcnt vmcnt(6)" ::: "memory")

#define RA(s, h) (((s) * 2 + (h)) * 8192)
#define RB(s, h) (32768 + ((s) * 2 + (h)) * 8192)

template <int OUT_BF16>
__global__ __launch_bounds__(512, 2) void gemm256_8ph(
    const u16* __restrict__ A, const u16* __restrict__ Bt, void* __restrict__ C,
    int lda, int ldb, int ldc, int Kd, int Ncols) {
  __shared__ u16 lds[65536];   // 128 KiB
  const int tid = threadIdx.x;
  const int lane = tid & 63, wv = tid >> 6;
  const int wm = wv >> 2, wn = wv & 3;       // 2M x 4N wave grid
  const int lm = lane & 15, lq = lane >> 4;
  const int bm = blockIdx.x * 256, bn = blockIdx.y * 256;
  const int NT = Kd >> 6;                    // K tiles (even)
  const int NT2 = NT >> 1;

  const int rofs = wv * 8 + (lane >> 3);                 // region row
  const int cel = ((lane & 7) ^ (lane >> 3)) * 8;        // col elems, swz

  auto stageH = [&](const u16* __restrict__ G, int rowBase, int ld, int kt,
                    int regU16) {
    const u16* g0 = G + (size_t)(rowBase + rofs) * ld + (kt << 6) + cel;
    gl_lds16(g0, &lds[regU16 + wv * 512]);
    const u16* g1 = G + (size_t)(rowBase + 64 + rofs) * ld + (kt << 6) + cel;
    gl_lds16(g1, &lds[regU16 + 4096 + wv * 512]);
  };

  s16x8 Af[4][2], Bf[4][2];
  f32x4 acc[8][4];
  const f32x4 z4 = {0.f, 0.f, 0.f, 0.f};
#pragma unroll
  for (int i = 0; i < 8; ++i)
#pragma unroll
    for (int j = 0; j < 4; ++j) acc[i][j] = z4;

  const int xorw = (lm & 7) << 3;   // read-side swizzle XOR in u16 units

#define DSA(s, mh)                                                          \
  _Pragma("unroll") for (int f = 0; f < 4; ++f)                             \
  _Pragma("unroll") for (int ks = 0; ks < 2; ++ks)                          \
    Af[f][ks] = *(const s16x8*)&lds[RA(s, wm) +                             \
      (((((mh) * 4 + f) * 16 + lm) * 64 + ((ks * 32 + lq * 8) ^ xorw)))];

#define DSB(s)                                                              \
  _Pragma("unroll") for (int f = 0; f < 4; ++f)                             \
  _Pragma("unroll") for (int ks = 0; ks < 2; ++ks)                          \
    Bf[f][ks] = *(const s16x8*)&lds[RB(s, wn >> 1) +                        \
      ((((wn & 1) * 64 + f * 16 + lm) * 64 + ((ks * 32 + lq * 8) ^ xorw)))];

#define QUAD(mh, nh)                                                        \
  do {                                                                      \
    __builtin_amdgcn_s_setprio(1);                                          \
    _Pragma("unroll") for (int f = 0; f < 4; ++f)                           \
    _Pragma("unroll") for (int n = 0; n < 2; ++n)                           \
    _Pragma("unroll") for (int ks = 0; ks < 2; ++ks)                        \
      acc[(mh) * 4 + f][(nh) * 2 + n] =                                     \
          __builtin_amdgcn_mfma_f32_16x16x32_bf16(                          \
              Af[f][ks], Bf[(nh) * 2 + n][ks],                              \
              acc[(mh) * 4 + f][(nh) * 2 + n], 0, 0, 0);                    \
    __builtin_amdgcn_s_setprio(0);                                          \
  } while (0)

  // ---- prologue: 7 halves (t0 full + t1 B0,B1,A0); t1A1 comes at p0 ----
  stageH(A, bm, lda, 0, RA(0, 0));
  stageH(A, bm + 128, lda, 0, RA(0, 1));
  stageH(Bt, bn, ldb, 0, RB(0, 0));
  stageH(Bt, bn + 128, ldb, 0, RB(0, 1));
  stageH(Bt, bn, ldb, 1, RB(1, 0));
  stageH(Bt, bn + 128, ldb, 1, RB(1, 1));
  stageH(A, bm, lda, 1, RA(1, 0));
  VMCNT6();        // first 4 halves (tile 0) landed
  SBAR();

#pragma unroll 1
  for (int t = 0; t < NT2; ++t) {
    const int T2 = 2 * t + 2, T3 = 2 * t + 3;
    // -------- tile 2t from slot 0 --------
    DSA(0, 0); DSB(0);
    stageH(A, bm + 128, lda, 2 * t + 1, RA(1, 1));   // s1A1 of tile 2t+1
    SBAR();
    QUAD(0, 0);
    SBAR();
    if (T2 < NT) stageH(Bt, bn, ldb, T2, RB(0, 0));
    SBAR();
    QUAD(0, 1);
    SBAR();
    DSA(0, 1);
    if (T2 < NT) stageH(Bt, bn + 128, ldb, T2, RB(0, 1));
    SBAR();
    QUAD(1, 0);
    SBAR();
    if (T2 < NT) stageH(A, bm, lda, T2, RA(0, 0));
    SBAR();
    QUAD(1, 1);
    VMCNT6();      // slot1 (tile 2t+1) fully landed before p4 reads
    SBAR();
    // -------- tile 2t+1 from slot 1 --------
    DSA(1, 0); DSB(1);
    if (T2 < NT) stageH(A, bm + 128, lda, T2, RA(0, 1));
    SBAR();
    QUAD(0, 0);
    SBAR();
    if (T3 < NT) stageH(Bt, bn, ldb, T3, RB(1, 0));
    SBAR();
    QUAD(0, 1);
    SBAR();
    DSA(1, 1);
    if (T3 < NT) stageH(Bt, bn + 128, ldb, T3, RB(1, 1));
    SBAR();
    QUAD(1, 0);
    SBAR();
    if (T3 < NT) stageH(A, bm, lda, T3, RA(1, 0));
    SBAR();
    QUAD(1, 1);
    VMCNT6();      // slot0 (tile 2t+2) fully landed before next p0 reads
    SBAR();
  }

  // epilogue: D col = lm, row = lq*4 + r within each 16x16 fragment
#pragma unroll
  for (int f = 0; f < 8; ++f) {
#pragma unroll
    for (int n = 0; n < 4; ++n) {
#pragma unroll
      for (int r = 0; r < 4; ++r) {
        const int row = bm + wm * 128 + f * 16 + lq * 4 + r;
        const int col = bn + wn * 64 + n * 16 + lm;
        if (col < Ncols) {
          if (OUT_BF16)
            ((u16*)C)[(size_t)row * ldc + col] = f2bf(acc[f][n][r]);
          else
            ((float*)C)[(size_t)row * ldc + col] = acc[f][n][r];
        }
      }
    }
  }
#undef DSA
#undef DSB
#undef QUAD
}

// ---------------- score GEMM: z[:,2048:2080] = x @ W_in[:,2048:2080] -----
__global__ __launch_bounds__(256) void score_gemm(
    const u16* __restrict__ A, const u16* __restrict__ Bt,
    u16* __restrict__ z) {
  __shared__ u16 As[8192];   // 16 units x 512 elems (128 rows x 64 k)
  __shared__ u16 Bs[2048];   // 4 units  (32 rows x 64 k)
  const int tid = threadIdx.x;
  const int lane = tid & 63, wv = tid >> 6;
  const int lm = lane & 15, lq = lane >> 4;
  const int bm = blockIdx.x * 128;

  const f32x4 z4 = {0.f, 0.f, 0.f, 0.f};
  f32x4 acc[2][2];
#pragma unroll
  for (int i = 0; i < 2; ++i)
#pragma unroll
    for (int j = 0; j < 2; ++j) acc[i][j] = z4;

  for (int k0 = 0; k0 < DD; k0 += 64) {
    __syncthreads();
#pragma unroll
    for (int t = 0; t < 5; ++t) {
      const int idx = wv * 5 + t;            // 0..19
      if (idx < 16) {                        // A unit (mt, kt)
        const int mt = idx >> 1, kt = idx & 1;
        const u16* g = A + (size_t)(bm + mt * 16 + lm) * DD + k0 + kt * 32 + lq * 8;
        gl_lds16(g, &As[idx * 512]);
      } else {                               // B unit (nt, kt)
        const int bidx = idx - 16;
        const int nt = bidx >> 1, kt = bidx & 1;
        const u16* g = Bt + (size_t)(2048 + nt * 16 + lm) * DD + k0 + kt * 32 + lq * 8;
        gl_lds16(g, &Bs[bidx * 512]);
      }
    }
    __syncthreads();
#pragma unroll
    for (int kt = 0; kt < 2; ++kt) {
      s16x8 af[2], bfb[2];
#pragma unroll
      for (int i = 0; i < 2; ++i) {
        const int mt = wv * 2 + i;
        af[i] = *(const s16x8*)&As[(mt * 2 + kt) * 512 + lane * 8];
        bfb[i] = *(const s16x8*)&Bs[(i * 2 + kt) * 512 + lane * 8];
      }
#pragma unroll
      for (int i = 0; i < 2; ++i)
#pragma unroll
        for (int j = 0; j < 2; ++j)
          acc[i][j] = __builtin_amdgcn_mfma_f32_16x16x32_bf16(af[i], bfb[j], acc[i][j], 0, 0, 0);
    }
  }
#pragma unroll
  for (int i = 0; i < 2; ++i)
#pragma unroll
    for (int j = 0; j < 2; ++j)
#pragma unroll
      for (int r = 0; r < 4; ++r) {
        const int row = bm + wv * 32 + i * 16 + lq * 4 + r;
        const int col = 2048 + j * 16 + lm;
        z[(size_t)row * ZLD + col] = f2bf(acc[i][j][r]);
      }
}

// ---------------- conv + p_w + features + chunk-local cumsum --------------
// One block = one 32-row chunk. Phase C stages each 35-row x 256-col z
// panel into LDS with s16x8 vector loads, then reads taps from LDS with
// a rolling register history. Chunk totals go to part[chunk].
__global__ __launch_bounds__(256) void conv_feat_scan(
    const u16* __restrict__ z, const float* __restrict__ kern,
    const float* __restrict__ theta, const float* __restrict__ decay,
    const float* __restrict__ anchor, const float* __restrict__ sscale,
    float* __restrict__ merged, float* __restrict__ part) {
  __shared__ float pbuf[CCH][KK];   // raw p_w per (row, head)
  __shared__ u16 zt[35 * 256];      // staged z panel (17.5 KB)
  const int tid = threadIdx.x;
  const int r0 = blockIdx.x * CCH;           // global row base
  const bool first = ((r0 & (LL - 1)) == 0);
  const int chunk = blockIdx.x;              // global chunk id

  // phase A: p_w for 32 rows x 32 heads (4 items/thread)
#pragma unroll
  for (int q = 0; q < 4; ++q) {
    const int item = q * 256 + tid;
    const int row = item >> 5, k = item & 31;
    float v = 0.f;
#pragma unroll
    for (int w = 0; w < CKK; ++w) {
      const int g = row + w;                 // offset from r0-3
      float zv = 0.f;
      if (!(first && g < 3))
        zv = bf2f(z[(size_t)(r0 - 3 + g) * ZLD + 2048 + k]);
      v = fmaf(zv, kern[w * ZC + 2048 + k], v);
    }
    const int l = (r0 + row) & (LL - 1);
    const float slope = (k < KK - AA) ? decay[k] : anchor[k - (KK - AA)];
    const float sp = log1pf(__expf(slope));
    const float lw = (k < KK - AA) ? (-sp * (float)(LL - 1 - l)) : (-sp * (float)l);
    pbuf[row][k] = __expf(sscale[k] * v + lw);
  }
  __syncthreads();

  // phase B: den chunk-local cumsum (32 threads; LDS reads conflict-free)
  if (tid < KK) {
    float run = 0.f;
#pragma unroll
    for (int row = 0; row < CCH; ++row) {
      run += pbuf[row][tid];
      merged[(size_t)(r0 + row) * ZC + tid] = run;
    }
    part[(size_t)chunk * ZC + tid] = run;
  }

  // phase C: features + chunk-local cumsum. Per it: stage 35x256 panel
  // (vector loads), then rolling 4-tap conv from LDS.
#pragma unroll 1
  for (int it = 0; it < 4; ++it) {
    __syncthreads();   // protect zt reuse (and pbuf/phase-B on it==0)
    for (int u = tid; u < 35 * 32; u += 256) {
      const int row = u >> 5, q8 = (u & 31) * 8;
      s16x8 v = {0, 0, 0, 0, 0, 0, 0, 0};
      if (!(first && row < 3))
        v = *(const s16x8*)(z + (size_t)(r0 - 3 + row) * ZLD + it * 256 + q8);
      *(s16x8*)&zt[row * 256 + q8] = v;
    }
    __syncthreads();

    const int c = it * 256 + tid;            // 0..1023
    const float kw0 = kern[0 * ZC + c], kw1 = kern[1 * ZC + c];
    const float kw2 = kern[2 * ZC + c], kw3 = kern[3 * ZC + c];
    const float th = theta[c];
    const int head = c >> 5;
    float h0 = bf2f(zt[0 * 256 + tid]);
    float h1 = bf2f(zt[1 * 256 + tid]);
    float h2 = bf2f(zt[2 * 256 + tid]);
    float sre = 0.f, sim = 0.f;
#pragma unroll 4
    for (int row = 0; row < CCH; ++row) {
      const float h3 = bf2f(zt[(row + 3) * 256 + tid]);
      float v = h0 * kw0;
      v = fmaf(h1, kw1, v);
      v = fmaf(h2, kw2, v);
      v = fmaf(h3, kw3, v);
      h0 = h1; h1 = h2; h2 = h3;
      const float phi = v * th;
      float sv, cv;
      __sincosf(phi, &sv, &cv);
      const float p = pbuf[row][head];
      sre = fmaf(p, cv, sre);
      sim = fmaf(p, sv, sim);
      float* mrow = merged + (size_t)(r0 + row) * ZC;
      mrow[KK + c] = sre;
      mrow[KK + FLATC + c] = sim;
    }
    part[(size_t)chunk * ZC + KK + c] = sre;
    part[(size_t)chunk * ZC + KK + FLATC + c] = sim;
  }
}

// ---------------- exclusive scan of chunk totals (128 chunks per b) -------
__global__ __launch_bounds__(256) void scan_offsets_kernel(float* __restrict__ part) {
  const int c = blockIdx.x * 256 + threadIdx.x;
  const int b = blockIdx.z;
  if (c >= ZC) return;
  float run = 0.f;
#pragma unroll 8
  for (int i = 0; i < NCHK; ++i) {
    const size_t idx = ((size_t)b * NCHK + i) * ZC + c;
    const float t = part[idx];
    part[idx] = run;
    run += t;
  }
}

// ---------------- fold norm_scale into head weights (bf16) ----------------
__global__ __launch_bounds__(256) void wprime_kernel(
    const float* __restrict__ W_re, const float* __restrict__ W_im,
    const float* __restrict__ ns, u16* __restrict__ wp) {
  const int i = blockIdx.x * 256 + threadIdx.x;   // 0..2047
  if (i < 1024) wp[i] = f2bf(ns[i >> 5] * W_re[i]);
  else {
    const int j = i - 1024;
    wp[i] = f2bf(ns[32 + (j >> 5)] * W_im[j]);
  }
}

// ---------------- norm_head via MFMA ----------------
// Block = 8 bl rows (4 waves x 2 rows). merged holds CHUNK-LOCAL cumsum;
// global prefix = chunk-local + part[chunk], added at load time.
// NEW: gate phase-split. Instead of recomputing the gate conv per MFMA
// output element (8 scalar LDS reads + exp each, 32 outputs/thread), a
// dedicated phase computes silu(conv(z_gate)) for all 8x1024 elements with
// VECTOR LDS reads (4 rows x 8 cols per thread), holds results in regs
// across a barrier, and writes them as f32 into an LDS overlay on the
// then-dead zw/skern region (deskewed +8 f32 per 128 cols). The MFMA
// epilogue then reads ONE conflict-free scalar f32 per output.
__global__ __launch_bounds__(256) void norm_head_mfma(
    float* merged, const u16* __restrict__ z, const float* __restrict__ kern,
    const u16* __restrict__ wp, const float* __restrict__ part) {
  // manual LDS partition: phase 1 zw(24992B)+skern(17280B) = 42272B;
  // phase 2 overlays sgf (8*SGLD*4 = 34560B) on the same region.
  __shared__ __align__(16) char smem[42272];
  u16* zw = (u16*)smem;                       // 11*GLD u16
  float* skern = (float*)(smem + 24992);      // 4*KLD f32
  float* sgf = (float*)smem;                  // 8*SGLD f32 (overlay)
  const int tid = threadIdx.x;
  const int r0 = blockIdx.x * 8;
  const bool first = ((r0 & (LL - 1)) == 0);
  const int lane = tid & 63, wv = tid >> 6;
  const int lm = lane & 15, lq = lane >> 4;
  // chunk offsets row for this block (8 rows always within one 32-row chunk)
  const float* po = part + (size_t)(blockIdx.x >> 2) * ZC;

  // stage z gate cols (1024..2047), rows r0-3 .. r0+7, with skew
  for (int idx = tid; idx < 11 * 128; idx += 256) {
    const int i = idx >> 7, c8 = idx & 127;
    s16x8 v = {0, 0, 0, 0, 0, 0, 0, 0};
    if (!(first && i < 3))
      v = *(const s16x8*)(z + (size_t)(r0 - 3 + i) * ZLD + 1024 + c8 * 8);
    *(s16x8*)&zw[i * GLD + c8 * 8 + (c8 >> 4) * 16] = v;
  }
  // stage gate conv weights (f32) with skew
  for (int idx = tid; idx < 4 * 256; idx += 256) {
    const int w = idx >> 8, c4 = idx & 255;
    float4 v = *(const float4*)(kern + w * ZC + 1024 + c4 * 4);
    *(float4*)&skern[w * KLD + c4 * 4 + (c4 >> 5) * 8] = v;
  }

  // B fragments (same for all rows): lane(lm,lq) holds W'[lq*8+j][nt*16+lm]
  s16x8 bre[2], bim[2];
#pragma unroll
  for (int nt = 0; nt < 2; ++nt)
#pragma unroll
    for (int jj = 0; jj < 8; ++jj) {
      bre[nt][jj] = (short)wp[(lq * 8 + jj) * 32 + nt * 16 + lm];
      bim[nt][jj] = (short)wp[1024 + (lq * 8 + jj) * 32 + nt * 16 + lm];
    }
  __syncthreads();

  // ---- gate phase: silu(conv) for rows rh*4..+3, cols cb..cb+7 ----
  const int rh = tid >> 7;            // 0..1
  const int cb = (tid & 127) * 8;     // col base 0..1016
  float gbuf[4][8];
  {
    const int sc = cb + (cb >> 7) * 8;     // skern skewed col base
    const int szb = cb + (cb >> 7) * 16;   // zw skewed col base
#pragma unroll
    for (int j = 0; j < 4; ++j) {
      const int rr = rh * 4 + j;
      float gv[8] = {0.f, 0.f, 0.f, 0.f, 0.f, 0.f, 0.f, 0.f};
#pragma unroll
      for (int w_ = 0; w_ < 4; ++w_) {
        s16x8 zv = *(const s16x8*)&zw[(rr + w_) * GLD + szb];
        float4 ka = *(const float4*)&skern[w_ * KLD + sc];
        float4 kb = *(const float4*)&skern[w_ * KLD + sc + 4];
        gv[0] = fmaf(bf2f((u16)zv[0]), ka.x, gv[0]);
        gv[1] = fmaf(bf2f((u16)zv[1]), ka.y, gv[1]);
        gv[2] = fmaf(bf2f((u16)zv[2]), ka.z, gv[2]);
        gv[3] = fmaf(bf2f((u16)zv[3]), ka.w, gv[3]);
        gv[4] = fmaf(bf2f((u16)zv[4]), kb.x, gv[4]);
        gv[5] = fmaf(bf2f((u16)zv[5]), kb.y, gv[5]);
        gv[6] = fmaf(bf2f((u16)zv[6]), kb.z, gv[6]);
        gv[7] = fmaf(bf2f((u16)zv[7]), kb.w, gv[7]);
      }
#pragma unroll
      for (int e = 0; e < 8; ++e)
        gbuf[j][e] = gv[e] * (1.0f / (1.0f + __expf(-gv[e])));
    }
  }
  __syncthreads();   // all zw/skern reads complete
  {
    const int sgc = cb + (cb >> 7) * 8;    // sgf skewed col base
#pragma unroll
    for (int j = 0; j < 4; ++j) {
      float4 a = {gbuf[j][0], gbuf[j][1], gbuf[j][2], gbuf[j][3]};
      float4 b = {gbuf[j][4], gbuf[j][5], gbuf[j][6], gbuf[j][7]};
      *(float4*)&sgf[(rh * 4 + j) * SGLD + sgc] = a;
      *(float4*)&sgf[(rh * 4 + j) * SGLD + sgc + 4] = b;
    }
  }
  __syncthreads();   // sgf visible

  const f32x4 z4 = {0.f, 0.f, 0.f, 0.f};
#pragma unroll 1
  for (int rr2 = 0; rr2 < 2; ++rr2) {
    const int rr = wv * 2 + rr2;          // 0..7 within block
    const int bl = r0 + rr;
    float* row = merged + (size_t)bl * ZC;
    // den for BOTH k-halves, before any write to this row (+ chunk offset)
    const float den0 = row[lm] + po[lm];
    const float den1 = row[16 + lm] + po[16 + lm];

#pragma unroll
    for (int khalf = 0; khalf < 2; ++khalf) {
      // A loads: re/im for (bl, k = khalf*16+lm), hp = lq*8..lq*8+7
      const int co = KK + (khalf * 16 + lm) * 32 + lq * 8;
      const float* rp = row + co;
      const float* pp = po + co;
      float4 ra = *(const float4*)rp;
      float4 rb = *(const float4*)(rp + 4);
      float4 ia = *(const float4*)(rp + FLATC);
      float4 ib = *(const float4*)(rp + FLATC + 4);
      float4 qa = *(const float4*)pp;
      float4 qb = *(const float4*)(pp + 4);
      float4 ja = *(const float4*)(pp + FLATC);
      float4 jb = *(const float4*)(pp + FLATC + 4);
      ra.x += qa.x; ra.y += qa.y; ra.z += qa.z; ra.w += qa.w;
      rb.x += qb.x; rb.y += qb.y; rb.z += qb.z; rb.w += qb.w;
      ia.x += ja.x; ia.y += ja.y; ia.z += ja.z; ia.w += ja.w;
      ib.x += jb.x; ib.y += jb.y; ib.z += jb.z; ib.w += jb.w;

      float ssq = ra.x * ra.x + ra.y * ra.y + ra.z * ra.z + ra.w * ra.w +
                  rb.x * rb.x + rb.y * rb.y + rb.z * rb.z + rb.w * rb.w +
                  ia.x * ia.x + ia.y * ia.y + ia.z * ia.z + ia.w * ia.w +
                  ib.x * ib.x + ib.y * ib.y + ib.z * ib.z + ib.w * ib.w;
      ssq += __shfl_xor(ssq, 16);
      ssq += __shfl_xor(ssq, 32);
      const float den = khalf ? den1 : den0;
      const float inv = 1.0f / fmaxf(den, 1e-4f);
      const float scale = inv * rsqrtf(ssq * inv * inv * (1.0f / 64.0f) + 1e-5f);

      s16x8 afr, afi;
      afr[0] = (short)f2bf(ra.x * scale); afr[1] = (short)f2bf(ra.y * scale);
      afr[2] = (short)f2bf(ra.z * scale); afr[3] = (short)f2bf(ra.w * scale);
      afr[4] = (short)f2bf(rb.x * scale); afr[5] = (short)f2bf(rb.y * scale);
      afr[6] = (short)f2bf(rb.z * scale); afr[7] = (short)f2bf(rb.w * scale);
      afi[0] = (short)f2bf(ia.x * scale); afi[1] = (short)f2bf(ia.y * scale);
      afi[2] = (short)f2bf(ia.z * scale); afi[3] = (short)f2bf(ia.w * scale);
      afi[4] = (short)f2bf(ib.x * scale); afi[5] = (short)f2bf(ib.y * scale);
      afi[6] = (short)f2bf(ib.z * scale); afi[7] = (short)f2bf(ib.w * scale);

      f32x4 acc[2];
#pragma unroll
      for (int nt = 0; nt < 2; ++nt) {
        acc[nt] = __builtin_amdgcn_mfma_f32_16x16x32_bf16(afr, bre[nt], z4, 0, 0, 0);
        acc[nt] = __builtin_amdgcn_mfma_f32_16x16x32_bf16(afi, bim[nt], acc[nt], 0, 0, 0);
      }

      // epilogue: D row = lq*4+r (k offset), col = lm (h offset)
      u16* grow = (u16*)row;
#pragma unroll
      for (int nt = 0; nt < 2; ++nt) {
#pragma unroll
        for (int r = 0; r < 4; ++r) {
          const int k = khalf * 16 + lq * 4 + r;
          const int o = k * 32 + nt * 16 + lm;
          const float sil = sgf[rr * SGLD + o + (o >> 7) * 8];
          grow[o] = f2bf(acc[nt][r] * sil);
        }
      }
    }
  }
}

// ---------------- launch ----------------
extern "C" void kernel_launch(void* const* d_in, const int* in_sizes, int n_in,
                              void* d_out, int out_size, void* d_ws, size_t ws_size,
                              hipStream_t stream) {
  const float* x      = (const float*)d_in[0];
  const float* W_in   = (const float*)d_in[1];
  const float* kern   = (const float*)d_in[2];
  const float* theta  = (const float*)d_in[3];
  const float* decay  = (const float*)d_in[4];
  const float* anchor = (const float*)d_in[5];
  const float* sscale = (const float*)d_in[6];
  const float* W_re   = (const float*)d_in[7];
  const float* W_im   = (const float*)d_in[8];
  const float* nscale = (const float*)d_in[9];
  const float* W_out  = (const float*)d_in[10];
  float* out = (float*)d_out;

  // workspace layout (~199.3 MiB used; fits the proven budget):
  //   merged [136.31 MB] | zbf [68.16 MB] | wp [4 KB] | wbt [4.26 MB] | slack
  // part (512 x 2080 f32 = 4.26 MB) ALIASES wbt: wbt dead after GEMM1+
  // score_gemm, part written by conv_feat_scan afterwards (stream-ordered).
  char* w = (char*)d_ws;
  float* merged = (float*)w;
  u16* xbf = (u16*)w;                                  // alias: dead once gemm1 done
  u16* zbf = (u16*)(w + (size_t)BL * ZC * 4);
  u16* wobt = zbf;                                     // alias: written after norm_head
  u16* wp = (u16*)(w + (size_t)BL * ZC * 4 + (size_t)BL * ZLD * 2);
  u16* wbt = wp + 2048;
  float* part = (float*)wbt;                           // alias (see above)

  // 1) casts / transposes / weight fold
  cast_bf16_kernel<<<dim3(BL * DD / 8 / 256), 256, 0, stream>>>(x, xbf, BL * DD);
  transpose_cast_kernel<<<dim3(32, 68), 256, 0, stream>>>(W_in, wbt, DD, ZC, NPAD);
  wprime_kernel<<<dim3(8), 256, 0, stream>>>(W_re, W_im, nscale, wp);

  // 2a) score cols 2048..2079 of z (tiny GEMM, removes the 9th col tile)
  score_gemm<<<dim3(BL / 128), 256, 0, stream>>>(xbf, wbt, zbf);

  // 2b) GEMM1 main: z[:, :2048] = x @ W_in[:, :2048]. grid = 64x8 = 512
  // blocks = exactly 2 clean dispatch rounds at 1 block/CU.
  gemm256_8ph<1><<<dim3(BL / 256, 8), 512, 0, stream>>>(
      xbf, wbt, zbf, DD, DD, ZLD, DD, ZC);

  // 3) conv + p_w + features + chunk-local cumsum -> merged, part
  conv_feat_scan<<<dim3(BL / CCH), 256, 0, stream>>>(
      zbf, kern, theta, decay, anchor, sscale, merged, part);

  // 4) exclusive scan of chunk totals (in-place on part)
  {
    dim3 grid2((ZC + 255) / 256, 1, BB);
    scan_offsets_kernel<<<grid2, 256, 0, stream>>>(part);
  }

  // 5) normalize + RMS + head matmuls (MFMA) + gate -> g (bf16, in-place)
  norm_head_mfma<<<dim3(BL / 8), 256, 0, stream>>>(merged, zbf, kern, wp, part);

  // 6) W_out^T (into dead z region), then GEMM2: out = g @ W_out (f32 out)
  transpose_cast_kernel<<<dim3(32, 32), 256, 0, stream>>>(W_out, wobt, DI, DD, DD);
  gemm256_8ph<0><<<dim3(BL / 256, DD / 256), 512, 0, stream>>>(
      (const u16*)merged, wobt, out, 2 * ZC, DI, DD, DI, DD);
}

// Round 9
// 349.143 us; speedup vs baseline: 1.1834x; 1.0341x over previous
//
#include <hip/hip_runtime.h>
#include <hip/hip_bf16.h>
#include <math.h>

// ---------------- static problem config ----------------
#define BB 4
#define LL 4096
#define DD 1024
#define KK 32
#define HH 32
#define AA 4
#define CKK 4
#define DI 1024
#define ZC 2080            // 2*DI + KK
#define FLATC 1024         // K*H
#define BL (BB * LL)       // 16384
#define ZLD 2080           // z row stride (bf16)
#define NPAD 2176          // W_in^T padded rows (17*128)

// scan config: chunk == conv block == 32 rows
#define CCH 32
#define NCHK (LL / CCH)    // 128 chunks per b

// norm_head LDS strides (skewed to break lq-stride-128 bank conflicts)
#define GLD 1136           // zw row stride in u16 : col = o + (o>>7)*16
#define KLD 1080           // skern row stride in f32: col = o + (o>>7)*8
#define SGLD 1080          // sgf (silu-gate f32) row stride: col = o + (o>>7)*8

typedef unsigned short u16;
typedef __attribute__((ext_vector_type(8))) short s16x8;
typedef __attribute__((ext_vector_type(4))) float f32x4;

__device__ __forceinline__ u16 f2bf(float f) {
  union { float f; unsigned int u; } v; v.f = f;
  unsigned int r = (v.u + 0x7FFFu + ((v.u >> 16) & 1u)) >> 16;
  return (u16)r;
}
__device__ __forceinline__ float bf2f(u16 u) {
  union { unsigned int i; float f; } x; x.i = ((unsigned int)u) << 16; return x.f;
}
__device__ __forceinline__ void gl_lds16(const void* g, void* l) {
  __builtin_amdgcn_global_load_lds(
      (const __attribute__((address_space(1))) unsigned int*)g,
      (__attribute__((address_space(3))) unsigned int*)l, 16, 0, 0);
}

// ---------------- fused prep: cast x + W_in^T + W_out^T + wprime ----------
// One dispatch replaces four. Block ranges:
//   [0, 8192)            cast x f32->bf16 (8 elems/thread)
//   [8192, 8192+2176)    W_in transpose tile (32x68 tiles)
//   [+1024)              W_out transpose tile (32x32 tiles)
//   [+8)                 wprime (norm_scale fold)
__global__ __launch_bounds__(256) void prep_kernel(
    const float* __restrict__ x, u16* __restrict__ xbf,
    const float* __restrict__ W_in, u16* __restrict__ wbt,
    const float* __restrict__ W_out, u16* __restrict__ wobt,
    const float* __restrict__ W_re, const float* __restrict__ W_im,
    const float* __restrict__ ns, u16* __restrict__ wp) {
  __shared__ float t[32][33];
  const int bid = blockIdx.x;
  const int tid = threadIdx.x;
  if (bid < 8192) {                       // cast x
    const int i = (bid * 256 + tid) * 8;
    float4 a = *(const float4*)(x + i);
    float4 b = *(const float4*)(x + i + 4);
    s16x8 v;
    v[0] = (short)f2bf(a.x); v[1] = (short)f2bf(a.y);
    v[2] = (short)f2bf(a.z); v[3] = (short)f2bf(a.w);
    v[4] = (short)f2bf(b.x); v[5] = (short)f2bf(b.y);
    v[6] = (short)f2bf(b.z); v[7] = (short)f2bf(b.w);
    *(s16x8*)(xbf + i) = v;
    return;
  }
  if (bid >= 8192 + 2176 + 1024) {        // wprime
    const int i = (bid - (8192 + 2176 + 1024)) * 256 + tid;
    if (i < 1024) wp[i] = f2bf(ns[i >> 5] * W_re[i]);
    else {
      const int j = i - 1024;
      wp[i] = f2bf(ns[32 + (j >> 5)] * W_im[j]);
    }
    return;
  }
  // transpose tiles
  const float* src; u16* dst; int R, C, Cpad, r0, c0;
  if (bid < 8192 + 2176) {
    const int id = bid - 8192;
    src = W_in; dst = wbt; R = DD; C = ZC; Cpad = NPAD;
    r0 = (id & 31) * 32; c0 = (id >> 5) * 32;
  } else {
    const int id = bid - (8192 + 2176);
    src = W_out; dst = wobt; R = DI; C = DD; Cpad = DD;
    r0 = (id & 31) * 32; c0 = (id >> 5) * 32;
  }
  const int lr = tid >> 5, lc = tid & 31;
#pragma unroll
  for (int i = 0; i < 4; ++i) {
    const int r = r0 + i * 8 + lr, c = c0 + lc;
    float v = 0.f;
    if (r < R && c < C) v = src[(size_t)r * C + c];
    t[lc][i * 8 + lr] = v;
  }
  __syncthreads();
#pragma unroll
  for (int i = 0; i < 4; ++i) {
    const int dr = c0 + i * 8 + lr;
    const int dc = r0 + lc;
    if (dr < Cpad && dc < R) dst[(size_t)dr * R + dc] = f2bf(t[i * 8 + lr][lc]);
  }
}

// ---------------- 256x256 8-phase bf16 MFMA GEMM (T1+T2+T3+T4+T5) --------
// C[M,N] = A[M,K] * Bt[N,K]^T.  512 threads = 8 waves (2M x 4N), per-wave
// output 128x64 (8x4 fragments of 16x16), BK=64, NT = K/64 tiles (even).
//
// LDS 128KB: 8 half-regions of 16KB (128 rows x 64 cols bf16, row-major).
// 3-bit XOR swizzle: elem_col ^= (row&7)<<3; conflict-free (verified:
// SQ_LDS_BANK_CONFLICT 7.08M -> 0). global_load_lds writes LINEAR dest,
// swizzle applied by pre-swizzling the GLOBAL source column (rule #21).
// Counted vmcnt(6) at phases 3/7 only; raw s_barrier (no vmcnt(0) drain).
#define FENCE() asm volatile("" ::: "memory")
#define SBAR() do { FENCE(); __builtin_amdgcn_s_barrier(); FENCE(); } while (0)
#define VMCNT6() asm volatile("s_waitcnt vmcnt(6)" ::: "memory")

#define RA(s, h) (((s) * 2 + (h)) * 8192)
#define RB(s, h) (32768 + ((s) * 2 + (h)) * 8192)

template <int OUT_BF16>
__global__ __launch_bounds__(512, 2) void gemm256_8ph(
    const u16* __restrict__ A, const u16* __restrict__ Bt, void* __restrict__ C,
    int lda, int ldb, int ldc, int Kd, int Ncols) {
  __shared__ u16 lds[65536];   // 128 KiB
  const int tid = threadIdx.x;
  const int lane = tid & 63, wv = tid >> 6;
  const int wm = wv >> 2, wn = wv & 3;       // 2M x 4N wave grid
  const int lm = lane & 15, lq = lane >> 4;
  const int bm = blockIdx.x * 256, bn = blockIdx.y * 256;
  const int NT = Kd >> 6;                    // K tiles (even)
  const int NT2 = NT >> 1;

  const int rofs = wv * 8 + (lane >> 3);                 // region row
  const int cel = ((lane & 7) ^ (lane >> 3)) * 8;        // col elems, swz

  auto stageH = [&](const u16* __restrict__ G, int rowBase, int ld, int kt,
                    int regU16) {
    const u16* g0 = G + (size_t)(rowBase + rofs) * ld + (kt << 6) + cel;
    gl_lds16(g0, &lds[regU16 + wv * 512]);
    const u16* g1 = G + (size_t)(rowBase + 64 + rofs) * ld + (kt << 6) + cel;
    gl_lds16(g1, &lds[regU16 + 4096 + wv * 512]);
  };

  s16x8 Af[4][2], Bf[4][2];
  f32x4 acc[8][4];
  const f32x4 z4 = {0.f, 0.f, 0.f, 0.f};
#pragma unroll
  for (int i = 0; i < 8; ++i)
#pragma unroll
    for (int j = 0; j < 4; ++j) acc[i][j] = z4;

  const int xorw = (lm & 7) << 3;   // read-side swizzle XOR in u16 units

#define DSA(s, mh)                                                          \
  _Pragma("unroll") for (int f = 0; f < 4; ++f)                             \
  _Pragma("unroll") for (int ks = 0; ks < 2; ++ks)                          \
    Af[f][ks] = *(const s16x8*)&lds[RA(s, wm) +                             \
      (((((mh) * 4 + f) * 16 + lm) * 64 + ((ks * 32 + lq * 8) ^ xorw)))];

#define DSB(s)                                                              \
  _Pragma("unroll") for (int f = 0; f < 4; ++f)                             \
  _Pragma("unroll") for (int ks = 0; ks < 2; ++ks)                          \
    Bf[f][ks] = *(const s16x8*)&lds[RB(s, wn >> 1) +                        \
      ((((wn & 1) * 64 + f * 16 + lm) * 64 + ((ks * 32 + lq * 8) ^ xorw)))];

#define QUAD(mh, nh)                                                        \
  do {                                                                      \
    __builtin_amdgcn_s_setprio(1);                                          \
    _Pragma("unroll") for (int f = 0; f < 4; ++f)                           \
    _Pragma("unroll") for (int n = 0; n < 2; ++n)                           \
    _Pragma("unroll") for (int ks = 0; ks < 2; ++ks)                        \
      acc[(mh) * 4 + f][(nh) * 2 + n] =                                     \
          __builtin_amdgcn_mfma_f32_16x16x32_bf16(                          \
              Af[f][ks], Bf[(nh) * 2 + n][ks],                              \
              acc[(mh) * 4 + f][(nh) * 2 + n], 0, 0, 0);                    \
    __builtin_amdgcn_s_setprio(0);                                          \
  } while (0)

  // ---- prologue: 7 halves (t0 full + t1 B0,B1,A0); t1A1 comes at p0 ----
  stageH(A, bm, lda, 0, RA(0, 0));
  stageH(A, bm + 128, lda, 0, RA(0, 1));
  stageH(Bt, bn, ldb, 0, RB(0, 0));
  stageH(Bt, bn + 128, ldb, 0, RB(0, 1));
  stageH(Bt, bn, ldb, 1, RB(1, 0));
  stageH(Bt, bn + 128, ldb, 1, RB(1, 1));
  stageH(A, bm, lda, 1, RA(1, 0));
  VMCNT6();        // first 4 halves (tile 0) landed
  SBAR();

#pragma unroll 1
  for (int t = 0; t < NT2; ++t) {
    const int T2 = 2 * t + 2, T3 = 2 * t + 3;
    // -------- tile 2t from slot 0 --------
    DSA(0, 0); DSB(0);
    stageH(A, bm + 128, lda, 2 * t + 1, RA(1, 1));   // s1A1 of tile 2t+1
    SBAR();
    QUAD(0, 0);
    SBAR();
    if (T2 < NT) stageH(Bt, bn, ldb, T2, RB(0, 0));
    SBAR();
    QUAD(0, 1);
    SBAR();
    DSA(0, 1);
    if (T2 < NT) stageH(Bt, bn + 128, ldb, T2, RB(0, 1));
    SBAR();
    QUAD(1, 0);
    SBAR();
    if (T2 < NT) stageH(A, bm, lda, T2, RA(0, 0));
    SBAR();
    QUAD(1, 1);
    VMCNT6();      // slot1 (tile 2t+1) fully landed before p4 reads
    SBAR();
    // -------- tile 2t+1 from slot 1 --------
    DSA(1, 0); DSB(1);
    if (T2 < NT) stageH(A, bm + 128, lda, T2, RA(0, 1));
    SBAR();
    QUAD(0, 0);
    SBAR();
    if (T3 < NT) stageH(Bt, bn, ldb, T3, RB(1, 0));
    SBAR();
    QUAD(0, 1);
    SBAR();
    DSA(1, 1);
    if (T3 < NT) stageH(Bt, bn + 128, ldb, T3, RB(1, 1));
    SBAR();
    QUAD(1, 0);
    SBAR();
    if (T3 < NT) stageH(A, bm, lda, T3, RA(1, 0));
    SBAR();
    QUAD(1, 1);
    VMCNT6();      // slot0 (tile 2t+2) fully landed before next p0 reads
    SBAR();
  }

  // epilogue: D col = lm, row = lq*4 + r within each 16x16 fragment
#pragma unroll
  for (int f = 0; f < 8; ++f) {
#pragma unroll
    for (int n = 0; n < 4; ++n) {
#pragma unroll
      for (int r = 0; r < 4; ++r) {
        const int row = bm + wm * 128 + f * 16 + lq * 4 + r;
        const int col = bn + wn * 64 + n * 16 + lm;
        if (col < Ncols) {
          if (OUT_BF16)
            ((u16*)C)[(size_t)row * ldc + col] = f2bf(acc[f][n][r]);
          else
            ((float*)C)[(size_t)row * ldc + col] = acc[f][n][r];
        }
      }
    }
  }
#undef DSA
#undef DSB
#undef QUAD
}

// ---------------- score GEMM: z[:,2048:2080] = x @ W_in[:,2048:2080] -----
__global__ __launch_bounds__(256) void score_gemm(
    const u16* __restrict__ A, const u16* __restrict__ Bt,
    u16* __restrict__ z) {
  __shared__ u16 As[8192];   // 16 units x 512 elems (128 rows x 64 k)
  __shared__ u16 Bs[2048];   // 4 units  (32 rows x 64 k)
  const int tid = threadIdx.x;
  const int lane = tid & 63, wv = tid >> 6;
  const int lm = lane & 15, lq = lane >> 4;
  const int bm = blockIdx.x * 128;

  const f32x4 z4 = {0.f, 0.f, 0.f, 0.f};
  f32x4 acc[2][2];
#pragma unroll
  for (int i = 0; i < 2; ++i)
#pragma unroll
    for (int j = 0; j < 2; ++j) acc[i][j] = z4;

  for (int k0 = 0; k0 < DD; k0 += 64) {
    __syncthreads();
#pragma unroll
    for (int t = 0; t < 5; ++t) {
      const int idx = wv * 5 + t;            // 0..19
      if (idx < 16) {                        // A unit (mt, kt)
        const int mt = idx >> 1, kt = idx & 1;
        const u16* g = A + (size_t)(bm + mt * 16 + lm) * DD + k0 + kt * 32 + lq * 8;
        gl_lds16(g, &As[idx * 512]);
      } else {                               // B unit (nt, kt)
        const int bidx = idx - 16;
        const int nt = bidx >> 1, kt = bidx & 1;
        const u16* g = Bt + (size_t)(2048 + nt * 16 + lm) * DD + k0 + kt * 32 + lq * 8;
        gl_lds16(g, &Bs[bidx * 512]);
      }
    }
    __syncthreads();
#pragma unroll
    for (int kt = 0; kt < 2; ++kt) {
      s16x8 af[2], bfb[2];
#pragma unroll
      for (int i = 0; i < 2; ++i) {
        const int mt = wv * 2 + i;
        af[i] = *(const s16x8*)&As[(mt * 2 + kt) * 512 + lane * 8];
        bfb[i] = *(const s16x8*)&Bs[(i * 2 + kt) * 512 + lane * 8];
      }
#pragma unroll
      for (int i = 0; i < 2; ++i)
#pragma unroll
        for (int j = 0; j < 2; ++j)
          acc[i][j] = __builtin_amdgcn_mfma_f32_16x16x32_bf16(af[i], bfb[j], acc[i][j], 0, 0, 0);
    }
  }
#pragma unroll
  for (int i = 0; i < 2; ++i)
#pragma unroll
    for (int j = 0; j < 2; ++j)
#pragma unroll
      for (int r = 0; r < 4; ++r) {
        const int row = bm + wv * 32 + i * 16 + lq * 4 + r;
        const int col = 2048 + j * 16 + lm;
        z[(size_t)row * ZLD + col] = f2bf(acc[i][j][r]);
      }
}

// ---------------- conv + p_w + features + chunk-local cumsum --------------
// One block = one 32-row chunk. re/im chunk-local cumsums are stored BF16
// (mbf [BL][2048]): halves the 272 MB f32 merged roundtrip. Precision note:
// only the chunk-LOCAL part (<=32 terms) is rounded; the global offset
// (part, f32) dominates magnitude for later chunks, so effective relative
// error << bf16's 0.4%. den cumsum stays f32 in dbuf [BL][32].
__global__ __launch_bounds__(256) void conv_feat_scan(
    const u16* __restrict__ z, const float* __restrict__ kern,
    const float* __restrict__ theta, const float* __restrict__ decay,
    const float* __restrict__ anchor, const float* __restrict__ sscale,
    u16* __restrict__ mbf, float* __restrict__ dbuf,
    float* __restrict__ part) {
  __shared__ float pbuf[CCH][KK];   // raw p_w per (row, head)
  __shared__ u16 zt[35 * 256];      // staged z panel (17.5 KB)
  const int tid = threadIdx.x;
  const int r0 = blockIdx.x * CCH;           // global row base
  const bool first = ((r0 & (LL - 1)) == 0);
  const int chunk = blockIdx.x;              // global chunk id

  // phase A: p_w for 32 rows x 32 heads (4 items/thread)
#pragma unroll
  for (int q = 0; q < 4; ++q) {
    const int item = q * 256 + tid;
    const int row = item >> 5, k = item & 31;
    float v = 0.f;
#pragma unroll
    for (int w = 0; w < CKK; ++w) {
      const int g = row + w;                 // offset from r0-3
      float zv = 0.f;
      if (!(first && g < 3))
        zv = bf2f(z[(size_t)(r0 - 3 + g) * ZLD + 2048 + k]);
      v = fmaf(zv, kern[w * ZC + 2048 + k], v);
    }
    const int l = (r0 + row) & (LL - 1);
    const float slope = (k < KK - AA) ? decay[k] : anchor[k - (KK - AA)];
    const float sp = log1pf(__expf(slope));
    const float lw = (k < KK - AA) ? (-sp * (float)(LL - 1 - l)) : (-sp * (float)l);
    pbuf[row][k] = __expf(sscale[k] * v + lw);
  }
  __syncthreads();

  // phase B: den chunk-local cumsum -> dbuf f32 (32 threads)
  if (tid < KK) {
    float run = 0.f;
#pragma unroll
    for (int row = 0; row < CCH; ++row) {
      run += pbuf[row][tid];
      dbuf[(size_t)(r0 + row) * KK + tid] = run;
    }
    part[(size_t)chunk * ZC + tid] = run;
  }

  // phase C: features + chunk-local cumsum. Per it: stage 35x256 panel
  // (vector loads), then rolling 4-tap conv from LDS.
#pragma unroll 1
  for (int it = 0; it < 4; ++it) {
    __syncthreads();   // protect zt reuse (and pbuf/phase-B on it==0)
    for (int u = tid; u < 35 * 32; u += 256) {
      const int row = u >> 5, q8 = (u & 31) * 8;
      s16x8 v = {0, 0, 0, 0, 0, 0, 0, 0};
      if (!(first && row < 3))
        v = *(const s16x8*)(z + (size_t)(r0 - 3 + row) * ZLD + it * 256 + q8);
      *(s16x8*)&zt[row * 256 + q8] = v;
    }
    __syncthreads();

    const int c = it * 256 + tid;            // 0..1023
    const float kw0 = kern[0 * ZC + c], kw1 = kern[1 * ZC + c];
    const float kw2 = kern[2 * ZC + c], kw3 = kern[3 * ZC + c];
    const float th = theta[c];
    const int head = c >> 5;
    float h0 = bf2f(zt[0 * 256 + tid]);
    float h1 = bf2f(zt[1 * 256 + tid]);
    float h2 = bf2f(zt[2 * 256 + tid]);
    float sre = 0.f, sim = 0.f;
#pragma unroll 4
    for (int row = 0; row < CCH; ++row) {
      const float h3 = bf2f(zt[(row + 3) * 256 + tid]);
      float v = h0 * kw0;
      v = fmaf(h1, kw1, v);
      v = fmaf(h2, kw2, v);
      v = fmaf(h3, kw3, v);
      h0 = h1; h1 = h2; h2 = h3;
      const float phi = v * th;
      float sv, cv;
      __sincosf(phi, &sv, &cv);
      const float p = pbuf[row][head];
      sre = fmaf(p, cv, sre);
      sim = fmaf(p, sv, sim);
      u16* mrow = mbf + (size_t)(r0 + row) * 2048;
      mrow[c] = f2bf(sre);
      mrow[1024 + c] = f2bf(sim);
    }
    part[(size_t)chunk * ZC + KK + c] = sre;
    part[(size_t)chunk * ZC + KK + FLATC + c] = sim;
  }
}

// ---------------- exclusive scan of chunk totals (128 chunks per b) -------
__global__ __launch_bounds__(256) void scan_offsets_kernel(float* __restrict__ part) {
  const int c = blockIdx.x * 256 + threadIdx.x;
  const int b = blockIdx.z;
  if (c >= ZC) return;
  float run = 0.f;
#pragma unroll 8
  for (int i = 0; i < NCHK; ++i) {
    const size_t idx = ((size_t)b * NCHK + i) * ZC + c;
    const float t = part[idx];
    part[idx] = run;
    run += t;
  }
}

// ---------------- norm_head via MFMA ----------------
// Block = 8 bl rows (4 waves x 2 rows). mbf holds CHUNK-LOCAL cumsum bf16;
// global prefix = bf2f(local) + part[chunk] (f32), den from dbuf f32.
// Gate phase-split (round 8): silu(conv(z_gate)) precomputed for all 8x1024
// elements with vector LDS reads, stored f32 in an LDS overlay; the MFMA
// epilogue reads one conflict-free scalar per output. g written to a
// compact [BL][1024] bf16 buffer (GEMM2 lda = 1024).
__global__ __launch_bounds__(256) void norm_head_mfma(
    const u16* __restrict__ mbf, const float* __restrict__ dbuf,
    const u16* __restrict__ z, const float* __restrict__ kern,
    const u16* __restrict__ wp, const float* __restrict__ part,
    u16* __restrict__ g) {
  // manual LDS partition: phase 1 zw(24992B)+skern(17280B) = 42272B;
  // phase 2 overlays sgf (8*SGLD*4 = 34560B) on the same region.
  __shared__ __align__(16) char smem[42272];
  u16* zw = (u16*)smem;                       // 11*GLD u16
  float* skern = (float*)(smem + 24992);      // 4*KLD f32
  float* sgf = (float*)smem;                  // 8*SGLD f32 (overlay)
  const int tid = threadIdx.x;
  const int r0 = blockIdx.x * 8;
  const bool first = ((r0 & (LL - 1)) == 0);
  const int lane = tid & 63, wv = tid >> 6;
  const int lm = lane & 15, lq = lane >> 4;
  // chunk offsets row for this block (8 rows always within one 32-row chunk)
  const float* po = part + (size_t)(blockIdx.x >> 2) * ZC;

  // stage z gate cols (1024..2047), rows r0-3 .. r0+7, with skew
  for (int idx = tid; idx < 11 * 128; idx += 256) {
    const int i = idx >> 7, c8 = idx & 127;
    s16x8 v = {0, 0, 0, 0, 0, 0, 0, 0};
    if (!(first && i < 3))
      v = *(const s16x8*)(z + (size_t)(r0 - 3 + i) * ZLD + 1024 + c8 * 8);
    *(s16x8*)&zw[i * GLD + c8 * 8 + (c8 >> 4) * 16] = v;
  }
  // stage gate conv weights (f32) with skew
  for (int idx = tid; idx < 4 * 256; idx += 256) {
    const int w = idx >> 8, c4 = idx & 255;
    float4 v = *(const float4*)(kern + w * ZC + 1024 + c4 * 4);
    *(float4*)&skern[w * KLD + c4 * 4 + (c4 >> 5) * 8] = v;
  }

  // B fragments (same for all rows): lane(lm,lq) holds W'[lq*8+j][nt*16+lm]
  s16x8 bre[2], bim[2];
#pragma unroll
  for (int nt = 0; nt < 2; ++nt)
#pragma unroll
    for (int jj = 0; jj < 8; ++jj) {
      bre[nt][jj] = (short)wp[(lq * 8 + jj) * 32 + nt * 16 + lm];
      bim[nt][jj] = (short)wp[1024 + (lq * 8 + jj) * 32 + nt * 16 + lm];
    }
  __syncthreads();

  // ---- gate phase: silu(conv) for rows rh*4..+3, cols cb..cb+7 ----
  const int rh = tid >> 7;            // 0..1
  const int cb = (tid & 127) * 8;     // col base 0..1016
  float gbuf[4][8];
  {
    const int sc = cb + (cb >> 7) * 8;     // skern skewed col base
    const int szb = cb + (cb >> 7) * 16;   // zw skewed col base
#pragma unroll
    for (int j = 0; j < 4; ++j) {
      const int rr = rh * 4 + j;
      float gv[8] = {0.f, 0.f, 0.f, 0.f, 0.f, 0.f, 0.f, 0.f};
#pragma unroll
      for (int w_ = 0; w_ < 4; ++w_) {
        s16x8 zv = *(const s16x8*)&zw[(rr + w_) * GLD + szb];
        float4 ka = *(const float4*)&skern[w_ * KLD + sc];
        float4 kb = *(const float4*)&skern[w_ * KLD + sc + 4];
        gv[0] = fmaf(bf2f((u16)zv[0]), ka.x, gv[0]);
        gv[1] = fmaf(bf2f((u16)zv[1]), ka.y, gv[1]);
        gv[2] = fmaf(bf2f((u16)zv[2]), ka.z, gv[2]);
        gv[3] = fmaf(bf2f((u16)zv[3]), ka.w, gv[3]);
        gv[4] = fmaf(bf2f((u16)zv[4]), kb.x, gv[4]);
        gv[5] = fmaf(bf2f((u16)zv[5]), kb.y, gv[5]);
        gv[6] = fmaf(bf2f((u16)zv[6]), kb.z, gv[6]);
        gv[7] = fmaf(bf2f((u16)zv[7]), kb.w, gv[7]);
      }
#pragma unroll
      for (int e = 0; e < 8; ++e)
        gbuf[j][e] = gv[e] * (1.0f / (1.0f + __expf(-gv[e])));
    }
  }
  __syncthreads();   // all zw/skern reads complete
  {
    const int sgc = cb + (cb >> 7) * 8;    // sgf skewed col base
#pragma unroll
    for (int j = 0; j < 4; ++j) {
      float4 a = {gbuf[j][0], gbuf[j][1], gbuf[j][2], gbuf[j][3]};
      float4 b = {gbuf[j][4], gbuf[j][5], gbuf[j][6], gbuf[j][7]};
      *(float4*)&sgf[(rh * 4 + j) * SGLD + sgc] = a;
      *(float4*)&sgf[(rh * 4 + j) * SGLD + sgc + 4] = b;
    }
  }
  __syncthreads();   // sgf visible

  const f32x4 z4 = {0.f, 0.f, 0.f, 0.f};
#pragma unroll 1
  for (int rr2 = 0; rr2 < 2; ++rr2) {
    const int rr = wv * 2 + rr2;          // 0..7 within block
    const int bl = r0 + rr;
    const float* dd = dbuf + (size_t)bl * KK;
    const float den0 = dd[lm] + po[lm];
    const float den1 = dd[16 + lm] + po[16 + lm];

#pragma unroll
    for (int khalf = 0; khalf < 2; ++khalf) {
      // A loads: re/im bf16 for (bl, k = khalf*16+lm), hp = lq*8..lq*8+7
      const int co = (khalf * 16 + lm) * 32 + lq * 8;
      const u16* rp = mbf + (size_t)bl * 2048 + co;
      s16x8 vre = *(const s16x8*)rp;
      s16x8 vim = *(const s16x8*)(rp + 1024);
      const float* pp = po + KK + co;
      float4 qa = *(const float4*)pp;
      float4 qb = *(const float4*)(pp + 4);
      float4 ja = *(const float4*)(pp + FLATC);
      float4 jb = *(const float4*)(pp + FLATC + 4);
      float re[8], im[8];
      re[0] = bf2f((u16)vre[0]) + qa.x; re[1] = bf2f((u16)vre[1]) + qa.y;
      re[2] = bf2f((u16)vre[2]) + qa.z; re[3] = bf2f((u16)vre[3]) + qa.w;
      re[4] = bf2f((u16)vre[4]) + qb.x; re[5] = bf2f((u16)vre[5]) + qb.y;
      re[6] = bf2f((u16)vre[6]) + qb.z; re[7] = bf2f((u16)vre[7]) + qb.w;
      im[0] = bf2f((u16)vim[0]) + ja.x; im[1] = bf2f((u16)vim[1]) + ja.y;
      im[2] = bf2f((u16)vim[2]) + ja.z; im[3] = bf2f((u16)vim[3]) + ja.w;
      im[4] = bf2f((u16)vim[4]) + jb.x; im[5] = bf2f((u16)vim[5]) + jb.y;
      im[6] = bf2f((u16)vim[6]) + jb.z; im[7] = bf2f((u16)vim[7]) + jb.w;

      float ssq = 0.f;
#pragma unroll
      for (int e = 0; e < 8; ++e) {
        ssq = fmaf(re[e], re[e], ssq);
        ssq = fmaf(im[e], im[e], ssq);
      }
      ssq += __shfl_xor(ssq, 16);
      ssq += __shfl_xor(ssq, 32);
      const float den = khalf ? den1 : den0;
      const float inv = 1.0f / fmaxf(den, 1e-4f);
      const float scale = inv * rsqrtf(ssq * inv * inv * (1.0f / 64.0f) + 1e-5f);

      s16x8 afr, afi;
#pragma unroll
      for (int e = 0; e < 8; ++e) {
        afr[e] = (short)f2bf(re[e] * scale);
        afi[e] = (short)f2bf(im[e] * scale);
      }

      f32x4 acc[2];
#pragma unroll
      for (int nt = 0; nt < 2; ++nt) {
        acc[nt] = __builtin_amdgcn_mfma_f32_16x16x32_bf16(afr, bre[nt], z4, 0, 0, 0);
        acc[nt] = __builtin_amdgcn_mfma_f32_16x16x32_bf16(afi, bim[nt], acc[nt], 0, 0, 0);
      }

      // epilogue: D row = lq*4+r (k offset), col = lm (h offset)
      u16* grow = g + (size_t)bl * 1024;
#pragma unroll
      for (int nt = 0; nt < 2; ++nt) {
#pragma unroll
        for (int r = 0; r < 4; ++r) {
          const int k = khalf * 16 + lq * 4 + r;
          const int o = k * 32 + nt * 16 + lm;
          const float sil = sgf[rr * SGLD + o + (o >> 7) * 8];
          grow[o] = f2bf(acc[nt][r] * sil);
        }
      }
    }
  }
}

// ---------------- launch ----------------
extern "C" void kernel_launch(void* const* d_in, const int* in_sizes, int n_in,
                              void* d_out, int out_size, void* d_ws, size_t ws_size,
                              hipStream_t stream) {
  const float* x      = (const float*)d_in[0];
  const float* W_in   = (const float*)d_in[1];
  const float* kern   = (const float*)d_in[2];
  const float* theta  = (const float*)d_in[3];
  const float* decay  = (const float*)d_in[4];
  const float* anchor = (const float*)d_in[5];
  const float* sscale = (const float*)d_in[6];
  const float* W_re   = (const float*)d_in[7];
  const float* W_im   = (const float*)d_in[8];
  const float* nscale = (const float*)d_in[9];
  const float* W_out  = (const float*)d_in[10];
  float* out = (float*)d_out;

  // workspace layout (173.3 MiB total; < proven 199 MiB budget):
  //   mbf  [BL][2048] u16  @ 0          (67.11 MB)  xbf aliases (dead pre-conv)
  //   zbf  [BL][ZLD]  u16  @ 67108864   (68.16 MB)
  //   dbuf [BL][32]   f32  @ 135266304  ( 2.10 MB)
  //   part [512][ZC]  f32  @ 137363456  ( 4.26 MB)
  //   wp   [2048]     u16  @ 141623296  ( 4 KB)
  //   wbt  [NPAD][DD] u16  @ 141627392  ( 4.46 MB)
  //   g    [BL][1024] u16  @ 146083840  (33.55 MB)
  //   wobt [DD][DD]   u16  @ 179638272  ( 2.10 MB)
  char* w = (char*)d_ws;
  u16* mbf   = (u16*)w;
  u16* xbf   = (u16*)w;                          // alias: dead once gemm1 done
  u16* zbf   = (u16*)(w + 67108864ull);
  float* dbuf = (float*)(w + 135266304ull);
  float* part = (float*)(w + 137363456ull);
  u16* wp    = (u16*)(w + 141623296ull);
  u16* wbt   = (u16*)(w + 141627392ull);
  u16* g     = (u16*)(w + 146083840ull);
  u16* wobt  = (u16*)(w + 179638272ull);

  // 1) fused prep: cast x + W_in^T + W_out^T + wprime (one dispatch)
  prep_kernel<<<dim3(8192 + 2176 + 1024 + 8), 256, 0, stream>>>(
      x, xbf, W_in, wbt, W_out, wobt, W_re, W_im, nscale, wp);

  // 2a) score cols 2048..2079 of z (tiny GEMM, keeps main grid clean)
  score_gemm<<<dim3(BL / 128), 256, 0, stream>>>(xbf, wbt, zbf);

  // 2b) GEMM1 main: z[:, :2048] = x @ W_in[:, :2048]. grid = 64x8 = 512
  // blocks = exactly 2 clean dispatch rounds at 1 block/CU.
  gemm256_8ph<1><<<dim3(BL / 256, 8), 512, 0, stream>>>(
      xbf, wbt, zbf, DD, DD, ZLD, DD, ZC);

  // 3) conv + p_w + features + chunk-local cumsum -> mbf(bf16), dbuf, part
  conv_feat_scan<<<dim3(BL / CCH), 256, 0, stream>>>(
      zbf, kern, theta, decay, anchor, sscale, mbf, dbuf, part);

  // 4) exclusive scan of chunk totals (in-place on part)
  {
    dim3 grid2((ZC + 255) / 256, 1, BB);
    scan_offsets_kernel<<<grid2, 256, 0, stream>>>(part);
  }

  // 5) normalize + RMS + head matmuls (MFMA) + gate -> g (compact bf16)
  norm_head_mfma<<<dim3(BL / 8), 256, 0, stream>>>(
      mbf, dbuf, zbf, kern, wp, part, g);

  // 6) GEMM2: out = g @ W_out (f32 out), lda = 1024 compact
  gemm256_8ph<0><<<dim3(BL / 256, DD / 256), 512, 0, stream>>>(
      g, wobt, out, 1024, DD, DD, DI, DD);
}

// Round 10
// 340.938 us; speedup vs baseline: 1.2118x; 1.0241x over previous
//
#include <hip/hip_runtime.h>
#include <hip/hip_bf16.h>
#include <math.h>

// ---------------- static problem config ----------------
#define BB 4
#define LL 4096
#define DD 1024
#define KK 32
#define HH 32
#define AA 4
#define CKK 4
#define DI 1024
#define ZC 2080            // 2*DI + KK
#define FLATC 1024         // K*H
#define BL (BB * LL)       // 16384
#define ZLD 2080           // z row stride (bf16)
#define NPAD 2176          // W_in^T padded rows (17*128)

// scan config: chunk == conv block == 32 rows
#define CCH 32
#define NCHK (LL / CCH)    // 128 chunks per b

// norm_head LDS strides (skewed to break lq-stride-128 bank conflicts)
#define GLD 1136           // zw row stride in u16 : col = o + (o>>7)*16
#define SGLD 1080          // sgf (silu-gate f32) row stride: col = o + (o>>7)*8

typedef unsigned short u16;
typedef __attribute__((ext_vector_type(8))) short s16x8;
typedef __attribute__((ext_vector_type(4))) float f32x4;

__device__ __forceinline__ u16 f2bf(float f) {
  union { float f; unsigned int u; } v; v.f = f;
  unsigned int r = (v.u + 0x7FFFu + ((v.u >> 16) & 1u)) >> 16;
  return (u16)r;
}
__device__ __forceinline__ float bf2f(u16 u) {
  union { unsigned int i; float f; } x; x.i = ((unsigned int)u) << 16; return x.f;
}
__device__ __forceinline__ void gl_lds16(const void* g, void* l) {
  __builtin_amdgcn_global_load_lds(
      (const __attribute__((address_space(1))) unsigned int*)g,
      (__attribute__((address_space(3))) unsigned int*)l, 16, 0, 0);
}

// ---------------- fused prep: cast x + W_in^T + W_out^T + wprime ----------
__global__ __launch_bounds__(256) void prep_kernel(
    const float* __restrict__ x, u16* __restrict__ xbf,
    const float* __restrict__ W_in, u16* __restrict__ wbt,
    const float* __restrict__ W_out, u16* __restrict__ wobt,
    const float* __restrict__ W_re, const float* __restrict__ W_im,
    const float* __restrict__ ns, u16* __restrict__ wp) {
  __shared__ float t[32][33];
  const int bid = blockIdx.x;
  const int tid = threadIdx.x;
  if (bid < 8192) {                       // cast x
    const int i = (bid * 256 + tid) * 8;
    float4 a = *(const float4*)(x + i);
    float4 b = *(const float4*)(x + i + 4);
    s16x8 v;
    v[0] = (short)f2bf(a.x); v[1] = (short)f2bf(a.y);
    v[2] = (short)f2bf(a.z); v[3] = (short)f2bf(a.w);
    v[4] = (short)f2bf(b.x); v[5] = (short)f2bf(b.y);
    v[6] = (short)f2bf(b.z); v[7] = (short)f2bf(b.w);
    *(s16x8*)(xbf + i) = v;
    return;
  }
  if (bid >= 8192 + 2176 + 1024) {        // wprime
    const int i = (bid - (8192 + 2176 + 1024)) * 256 + tid;
    if (i < 1024) wp[i] = f2bf(ns[i >> 5] * W_re[i]);
    else {
      const int j = i - 1024;
      wp[i] = f2bf(ns[32 + (j >> 5)] * W_im[j]);
    }
    return;
  }
  // transpose tiles
  const float* src; u16* dst; int R, C, Cpad, r0, c0;
  if (bid < 8192 + 2176) {
    const int id = bid - 8192;
    src = W_in; dst = wbt; R = DD; C = ZC; Cpad = NPAD;
    r0 = (id & 31) * 32; c0 = (id >> 5) * 32;
  } else {
    const int id = bid - (8192 + 2176);
    src = W_out; dst = wobt; R = DI; C = DD; Cpad = DD;
    r0 = (id & 31) * 32; c0 = (id >> 5) * 32;
  }
  const int lr = tid >> 5, lc = tid & 31;
#pragma unroll
  for (int i = 0; i < 4; ++i) {
    const int r = r0 + i * 8 + lr, c = c0 + lc;
    float v = 0.f;
    if (r < R && c < C) v = src[(size_t)r * C + c];
    t[lc][i * 8 + lr] = v;
  }
  __syncthreads();
#pragma unroll
  for (int i = 0; i < 4; ++i) {
    const int dr = c0 + i * 8 + lr;
    const int dc = r0 + lc;
    if (dr < Cpad && dc < R) dst[(size_t)dr * R + dc] = f2bf(t[i * 8 + lr][lc]);
  }
}

// ---------------- 256x256 8-phase bf16 MFMA GEMM (T1+T2+T3+T4+T5) --------
// C[M,N] = A[M,K] * Bt[N,K]^T.  512 threads = 8 waves (2M x 4N), per-wave
// output 128x64 (8x4 fragments of 16x16), BK=64, NT = K/64 tiles (even).
//
// LDS 128KB: 8 half-regions of 16KB (128 rows x 64 cols bf16, row-major).
// 3-bit XOR swizzle: elem_col ^= (row&7)<<3; conflict-free (verified:
// SQ_LDS_BANK_CONFLICT 7.08M -> 0). global_load_lds writes LINEAR dest,
// swizzle applied by pre-swizzling the GLOBAL source column (rule #21).
// Counted vmcnt(6) at phases 3/7 only; raw s_barrier (no vmcnt(0) drain).
#define FENCE() asm volatile("" ::: "memory")
#define SBAR() do { FENCE(); __builtin_amdgcn_s_barrier(); FENCE(); } while (0)
#define VMCNT6() asm volatile("s_waitcnt vmcnt(6)" ::: "memory")

#define RA(s, h) (((s) * 2 + (h)) * 8192)
#define RB(s, h) (32768 + ((s) * 2 + (h)) * 8192)

template <int OUT_BF16>
__global__ __launch_bounds__(512, 2) void gemm256_8ph(
    const u16* __restrict__ A, const u16* __restrict__ Bt, void* __restrict__ C,
    int lda, int ldb, int ldc, int Kd, int Ncols) {
  __shared__ u16 lds[65536];   // 128 KiB
  const int tid = threadIdx.x;
  const int lane = tid & 63, wv = tid >> 6;
  const int wm = wv >> 2, wn = wv & 3;       // 2M x 4N wave grid
  const int lm = lane & 15, lq = lane >> 4;
  const int bm = blockIdx.x * 256, bn = blockIdx.y * 256;
  const int NT = Kd >> 6;                    // K tiles (even)
  const int NT2 = NT >> 1;

  const int rofs = wv * 8 + (lane >> 3);                 // region row
  const int cel = ((lane & 7) ^ (lane >> 3)) * 8;        // col elems, swz

  auto stageH = [&](const u16* __restrict__ G, int rowBase, int ld, int kt,
                    int regU16) {
    const u16* g0 = G + (size_t)(rowBase + rofs) * ld + (kt << 6) + cel;
    gl_lds16(g0, &lds[regU16 + wv * 512]);
    const u16* g1 = G + (size_t)(rowBase + 64 + rofs) * ld + (kt << 6) + cel;
    gl_lds16(g1, &lds[regU16 + 4096 + wv * 512]);
  };

  s16x8 Af[4][2], Bf[4][2];
  f32x4 acc[8][4];
  const f32x4 z4 = {0.f, 0.f, 0.f, 0.f};
#pragma unroll
  for (int i = 0; i < 8; ++i)
#pragma unroll
    for (int j = 0; j < 4; ++j) acc[i][j] = z4;

  const int xorw = (lm & 7) << 3;   // read-side swizzle XOR in u16 units

#define DSA(s, mh)                                                          \
  _Pragma("unroll") for (int f = 0; f < 4; ++f)                             \
  _Pragma("unroll") for (int ks = 0; ks < 2; ++ks)                          \
    Af[f][ks] = *(const s16x8*)&lds[RA(s, wm) +                             \
      (((((mh) * 4 + f) * 16 + lm) * 64 + ((ks * 32 + lq * 8) ^ xorw)))];

#define DSB(s)                                                              \
  _Pragma("unroll") for (int f = 0; f < 4; ++f)                             \
  _Pragma("unroll") for (int ks = 0; ks < 2; ++ks)                          \
    Bf[f][ks] = *(const s16x8*)&lds[RB(s, wn >> 1) +                        \
      ((((wn & 1) * 64 + f * 16 + lm) * 64 + ((ks * 32 + lq * 8) ^ xorw)))];

#define QUAD(mh, nh)                                                        \
  do {                                                                      \
    __builtin_amdgcn_s_setprio(1);                                          \
    _Pragma("unroll") for (int f = 0; f < 4; ++f)                           \
    _Pragma("unroll") for (int n = 0; n < 2; ++n)                           \
    _Pragma("unroll") for (int ks = 0; ks < 2; ++ks)                        \
      acc[(mh) * 4 + f][(nh) * 2 + n] =                                     \
          __builtin_amdgcn_mfma_f32_16x16x32_bf16(                          \
              Af[f][ks], Bf[(nh) * 2 + n][ks],                              \
              acc[(mh) * 4 + f][(nh) * 2 + n], 0, 0, 0);                    \
    __builtin_amdgcn_s_setprio(0);                                          \
  } while (0)

  // ---- prologue: 7 halves (t0 full + t1 B0,B1,A0); t1A1 comes at p0 ----
  stageH(A, bm, lda, 0, RA(0, 0));
  stageH(A, bm + 128, lda, 0, RA(0, 1));
  stageH(Bt, bn, ldb, 0, RB(0, 0));
  stageH(Bt, bn + 128, ldb, 0, RB(0, 1));
  stageH(Bt, bn, ldb, 1, RB(1, 0));
  stageH(Bt, bn + 128, ldb, 1, RB(1, 1));
  stageH(A, bm, lda, 1, RA(1, 0));
  VMCNT6();        // first 4 halves (tile 0) landed
  SBAR();

#pragma unroll 1
  for (int t = 0; t < NT2; ++t) {
    const int T2 = 2 * t + 2, T3 = 2 * t + 3;
    // -------- tile 2t from slot 0 --------
    DSA(0, 0); DSB(0);
    stageH(A, bm + 128, lda, 2 * t + 1, RA(1, 1));   // s1A1 of tile 2t+1
    SBAR();
    QUAD(0, 0);
    SBAR();
    if (T2 < NT) stageH(Bt, bn, ldb, T2, RB(0, 0));
    SBAR();
    QUAD(0, 1);
    SBAR();
    DSA(0, 1);
    if (T2 < NT) stageH(Bt, bn + 128, ldb, T2, RB(0, 1));
    SBAR();
    QUAD(1, 0);
    SBAR();
    if (T2 < NT) stageH(A, bm, lda, T2, RA(0, 0));
    SBAR();
    QUAD(1, 1);
    VMCNT6();      // slot1 (tile 2t+1) fully landed before p4 reads
    SBAR();
    // -------- tile 2t+1 from slot 1 --------
    DSA(1, 0); DSB(1);
    if (T2 < NT) stageH(A, bm + 128, lda, T2, RA(0, 1));
    SBAR();
    QUAD(0, 0);
    SBAR();
    if (T3 < NT) stageH(Bt, bn, ldb, T3, RB(1, 0));
    SBAR();
    QUAD(0, 1);
    SBAR();
    DSA(1, 1);
    if (T3 < NT) stageH(Bt, bn + 128, ldb, T3, RB(1, 1));
    SBAR();
    QUAD(1, 0);
    SBAR();
    if (T3 < NT) stageH(A, bm, lda, T3, RA(1, 0));
    SBAR();
    QUAD(1, 1);
    VMCNT6();      // slot0 (tile 2t+2) fully landed before next p0 reads
    SBAR();
  }

  // epilogue: D col = lm, row = lq*4 + r within each 16x16 fragment
#pragma unroll
  for (int f = 0; f < 8; ++f) {
#pragma unroll
    for (int n = 0; n < 4; ++n) {
#pragma unroll
      for (int r = 0; r < 4; ++r) {
        const int row = bm + wm * 128 + f * 16 + lq * 4 + r;
        const int col = bn + wn * 64 + n * 16 + lm;
        if (col < Ncols) {
          if (OUT_BF16)
            ((u16*)C)[(size_t)row * ldc + col] = f2bf(acc[f][n][r]);
          else
            ((float*)C)[(size_t)row * ldc + col] = acc[f][n][r];
        }
      }
    }
  }
#undef DSA
#undef DSB
#undef QUAD
}

// ---------------- score GEMM: z[:,2048:2080] = x @ W_in[:,2048:2080] -----
__global__ __launch_bounds__(256) void score_gemm(
    const u16* __restrict__ A, const u16* __restrict__ Bt,
    u16* __restrict__ z) {
  __shared__ u16 As[8192];   // 16 units x 512 elems (128 rows x 64 k)
  __shared__ u16 Bs[2048];   // 4 units  (32 rows x 64 k)
  const int tid = threadIdx.x;
  const int lane = tid & 63, wv = tid >> 6;
  const int lm = lane & 15, lq = lane >> 4;
  const int bm = blockIdx.x * 128;

  const f32x4 z4 = {0.f, 0.f, 0.f, 0.f};
  f32x4 acc[2][2];
#pragma unroll
  for (int i = 0; i < 2; ++i)
#pragma unroll
    for (int j = 0; j < 2; ++j) acc[i][j] = z4;

  for (int k0 = 0; k0 < DD; k0 += 64) {
    __syncthreads();
#pragma unroll
    for (int t = 0; t < 5; ++t) {
      const int idx = wv * 5 + t;            // 0..19
      if (idx < 16) {                        // A unit (mt, kt)
        const int mt = idx >> 1, kt = idx & 1;
        const u16* g = A + (size_t)(bm + mt * 16 + lm) * DD + k0 + kt * 32 + lq * 8;
        gl_lds16(g, &As[idx * 512]);
      } else {                               // B unit (nt, kt)
        const int bidx = idx - 16;
        const int nt = bidx >> 1, kt = bidx & 1;
        const u16* g = Bt + (size_t)(2048 + nt * 16 + lm) * DD + k0 + kt * 32 + lq * 8;
        gl_lds16(g, &Bs[bidx * 512]);
      }
    }
    __syncthreads();
#pragma unroll
    for (int kt = 0; kt < 2; ++kt) {
      s16x8 af[2], bfb[2];
#pragma unroll
      for (int i = 0; i < 2; ++i) {
        const int mt = wv * 2 + i;
        af[i] = *(const s16x8*)&As[(mt * 2 + kt) * 512 + lane * 8];
        bfb[i] = *(const s16x8*)&Bs[(i * 2 + kt) * 512 + lane * 8];
      }
#pragma unroll
      for (int i = 0; i < 2; ++i)
#pragma unroll
        for (int j = 0; j < 2; ++j)
          acc[i][j] = __builtin_amdgcn_mfma_f32_16x16x32_bf16(af[i], bfb[j], acc[i][j], 0, 0, 0);
    }
  }
#pragma unroll
  for (int i = 0; i < 2; ++i)
#pragma unroll
    for (int j = 0; j < 2; ++j)
#pragma unroll
      for (int r = 0; r < 4; ++r) {
        const int row = bm + wv * 32 + i * 16 + lq * 4 + r;
        const int col = 2048 + j * 16 + lm;
        z[(size_t)row * ZLD + col] = f2bf(acc[i][j][r]);
      }
}

// ---------------- conv + p_w + features + chunk-local cumsum --------------
// One block = one 32-row chunk. re/im chunk-local cumsums stored BF16
// (mbf [BL][2048]); den cumsum f32 in dbuf. Phase A now reads the score
// columns from a vector-staged LDS panel (st) instead of 16 scalar 2B
// global loads per thread (G13).
__global__ __launch_bounds__(256) void conv_feat_scan(
    const u16* __restrict__ z, const float* __restrict__ kern,
    const float* __restrict__ theta, const float* __restrict__ decay,
    const float* __restrict__ anchor, const float* __restrict__ sscale,
    u16* __restrict__ mbf, float* __restrict__ dbuf,
    float* __restrict__ part) {
  __shared__ float pbuf[CCH][KK];   // raw p_w per (row, head)
  __shared__ u16 zt[35 * 256];      // staged z panel (17.5 KB)
  __shared__ u16 st[35 * 32];       // staged score panel (2.2 KB)
  const int tid = threadIdx.x;
  const int r0 = blockIdx.x * CCH;           // global row base
  const bool first = ((r0 & (LL - 1)) == 0);
  const int chunk = blockIdx.x;              // global chunk id

  // stage score panel rows r0-3 .. r0+31 (35 x 32 u16, vectorized)
  if (tid < 140) {
    const int row = tid >> 2, q8 = (tid & 3) * 8;
    s16x8 v = {0, 0, 0, 0, 0, 0, 0, 0};
    if (!(first && row < 3))
      v = *(const s16x8*)(z + (size_t)(r0 - 3 + row) * ZLD + 2048 + q8);
    *(s16x8*)&st[row * 32 + q8] = v;
  }
  __syncthreads();

  // phase A: p_w for 32 rows x 32 heads (4 items/thread), scores from LDS
#pragma unroll
  for (int q = 0; q < 4; ++q) {
    const int item = q * 256 + tid;
    const int row = item >> 5, k = item & 31;
    float v = 0.f;
#pragma unroll
    for (int w = 0; w < CKK; ++w)
      v = fmaf(bf2f(st[(row + w) * 32 + k]), kern[w * ZC + 2048 + k], v);
    const int l = (r0 + row) & (LL - 1);
    const float slope = (k < KK - AA) ? decay[k] : anchor[k - (KK - AA)];
    const float sp = log1pf(__expf(slope));
    const float lw = (k < KK - AA) ? (-sp * (float)(LL - 1 - l)) : (-sp * (float)l);
    pbuf[row][k] = __expf(sscale[k] * v + lw);
  }
  __syncthreads();

  // phase B: den chunk-local cumsum -> dbuf f32 (32 threads)
  if (tid < KK) {
    float run = 0.f;
#pragma unroll
    for (int row = 0; row < CCH; ++row) {
      run += pbuf[row][tid];
      dbuf[(size_t)(r0 + row) * KK + tid] = run;
    }
    part[(size_t)chunk * ZC + tid] = run;
  }

  // phase C: features + chunk-local cumsum. Per it: stage 35x256 panel
  // (vector loads), then rolling 4-tap conv from LDS.
#pragma unroll 1
  for (int it = 0; it < 4; ++it) {
    __syncthreads();   // protect zt reuse (and pbuf/phase-B on it==0)
    for (int u = tid; u < 35 * 32; u += 256) {
      const int row = u >> 5, q8 = (u & 31) * 8;
      s16x8 v = {0, 0, 0, 0, 0, 0, 0, 0};
      if (!(first && row < 3))
        v = *(const s16x8*)(z + (size_t)(r0 - 3 + row) * ZLD + it * 256 + q8);
      *(s16x8*)&zt[row * 256 + q8] = v;
    }
    __syncthreads();

    const int c = it * 256 + tid;            // 0..1023
    const float kw0 = kern[0 * ZC + c], kw1 = kern[1 * ZC + c];
    const float kw2 = kern[2 * ZC + c], kw3 = kern[3 * ZC + c];
    const float th = theta[c];
    const int head = c >> 5;
    float h0 = bf2f(zt[0 * 256 + tid]);
    float h1 = bf2f(zt[1 * 256 + tid]);
    float h2 = bf2f(zt[2 * 256 + tid]);
    float sre = 0.f, sim = 0.f;
#pragma unroll 4
    for (int row = 0; row < CCH; ++row) {
      const float h3 = bf2f(zt[(row + 3) * 256 + tid]);
      float v = h0 * kw0;
      v = fmaf(h1, kw1, v);
      v = fmaf(h2, kw2, v);
      v = fmaf(h3, kw3, v);
      h0 = h1; h1 = h2; h2 = h3;
      const float phi = v * th;
      float sv, cv;
      __sincosf(phi, &sv, &cv);
      const float p = pbuf[row][head];
      sre = fmaf(p, cv, sre);
      sim = fmaf(p, sv, sim);
      u16* mrow = mbf + (size_t)(r0 + row) * 2048;
      mrow[c] = f2bf(sre);
      mrow[1024 + c] = f2bf(sim);
    }
    part[(size_t)chunk * ZC + KK + c] = sre;
    part[(size_t)chunk * ZC + KK + FLATC + c] = sim;
  }
}

// ---------------- exclusive scan of chunk totals (128 chunks per b) -------
__global__ __launch_bounds__(256) void scan_offsets_kernel(float* __restrict__ part) {
  const int c = blockIdx.x * 256 + threadIdx.x;
  const int b = blockIdx.z;
  if (c >= ZC) return;
  float run = 0.f;
#pragma unroll 8
  for (int i = 0; i < NCHK; ++i) {
    const size_t idx = ((size_t)b * NCHK + i) * ZC + c;
    const float t = part[idx];
    part[idx] = run;
    run += t;
  }
}

// ---------------- norm_head via MFMA ----------------
// Block = 8 bl rows (4 waves x 2 rows). mbf holds CHUNK-LOCAL cumsum bf16;
// global prefix = bf2f(local) + part[chunk] (f32), den from dbuf f32.
// Gate phase-split: silu(conv(z_gate)) precomputed for all 8x1024 elements
// with vector LDS z reads + DIRECT global kern f32 reads (skern LDS buffer
// removed -> LDS region 42.2KB -> 34.5KB -> 4 blocks/CU instead of 3:
// +33% TLP for this latency-bound kernel). sgf (f32 silu results) overlays
// the then-dead zw region. g written compact [BL][1024] bf16.
__global__ __launch_bounds__(256) void norm_head_mfma(
    const u16* __restrict__ mbf, const float* __restrict__ dbuf,
    const u16* __restrict__ z, const float* __restrict__ kern,
    const u16* __restrict__ wp, const float* __restrict__ part,
    u16* __restrict__ g) {
  // manual LDS partition: phase 1 zw (11*GLD*2 = 24992B);
  // phase 2 overlays sgf (8*SGLD*4 = 34560B) on the same region.
  __shared__ __align__(16) char smem[34560];
  u16* zw = (u16*)smem;                       // 11*GLD u16
  float* sgf = (float*)smem;                  // 8*SGLD f32 (overlay)
  const int tid = threadIdx.x;
  const int r0 = blockIdx.x * 8;
  const bool first = ((r0 & (LL - 1)) == 0);
  const int lane = tid & 63, wv = tid >> 6;
  const int lm = lane & 15, lq = lane >> 4;
  // chunk offsets row for this block (8 rows always within one 32-row chunk)
  const float* po = part + (size_t)(blockIdx.x >> 2) * ZC;

  // stage z gate cols (1024..2047), rows r0-3 .. r0+7, with skew
  for (int idx = tid; idx < 11 * 128; idx += 256) {
    const int i = idx >> 7, c8 = idx & 127;
    s16x8 v = {0, 0, 0, 0, 0, 0, 0, 0};
    if (!(first && i < 3))
      v = *(const s16x8*)(z + (size_t)(r0 - 3 + i) * ZLD + 1024 + c8 * 8);
    *(s16x8*)&zw[i * GLD + c8 * 8 + (c8 >> 4) * 16] = v;
  }

  // B fragments (same for all rows): lane(lm,lq) holds W'[lq*8+j][nt*16+lm]
  s16x8 bre[2], bim[2];
#pragma unroll
  for (int nt = 0; nt < 2; ++nt)
#pragma unroll
    for (int jj = 0; jj < 8; ++jj) {
      bre[nt][jj] = (short)wp[(lq * 8 + jj) * 32 + nt * 16 + lm];
      bim[nt][jj] = (short)wp[1024 + (lq * 8 + jj) * 32 + nt * 16 + lm];
    }
  __syncthreads();

  // ---- gate phase: silu(conv) for rows rh*4..+3, cols cb..cb+7 ----
  const int rh = tid >> 7;            // 0..1
  const int cb = (tid & 127) * 8;     // col base 0..1016
  float gbuf[4][8];
  {
    const int szb = cb + (cb >> 7) * 16;   // zw skewed col base
#pragma unroll
    for (int j = 0; j < 4; ++j) {
      const int rr = rh * 4 + j;
      float gv[8] = {0.f, 0.f, 0.f, 0.f, 0.f, 0.f, 0.f, 0.f};
#pragma unroll
      for (int w_ = 0; w_ < 4; ++w_) {
        s16x8 zv = *(const s16x8*)&zw[(rr + w_) * GLD + szb];
        float4 ka = *(const float4*)(kern + w_ * ZC + 1024 + cb);
        float4 kb = *(const float4*)(kern + w_ * ZC + 1024 + cb + 4);
        gv[0] = fmaf(bf2f((u16)zv[0]), ka.x, gv[0]);
        gv[1] = fmaf(bf2f((u16)zv[1]), ka.y, gv[1]);
        gv[2] = fmaf(bf2f((u16)zv[2]), ka.z, gv[2]);
        gv[3] = fmaf(bf2f((u16)zv[3]), ka.w, gv[3]);
        gv[4] = fmaf(bf2f((u16)zv[4]), kb.x, gv[4]);
        gv[5] = fmaf(bf2f((u16)zv[5]), kb.y, gv[5]);
        gv[6] = fmaf(bf2f((u16)zv[6]), kb.z, gv[6]);
        gv[7] = fmaf(bf2f((u16)zv[7]), kb.w, gv[7]);
      }
#pragma unroll
      for (int e = 0; e < 8; ++e)
        gbuf[j][e] = gv[e] * (1.0f / (1.0f + __expf(-gv[e])));
    }
  }
  __syncthreads();   // all zw reads complete (sgf overlays zw)
  {
    const int sgc = cb + (cb >> 7) * 8;    // sgf skewed col base
#pragma unroll
    for (int j = 0; j < 4; ++j) {
      float4 a = {gbuf[j][0], gbuf[j][1], gbuf[j][2], gbuf[j][3]};
      float4 b = {gbuf[j][4], gbuf[j][5], gbuf[j][6], gbuf[j][7]};
      *(float4*)&sgf[(rh * 4 + j) * SGLD + sgc] = a;
      *(float4*)&sgf[(rh * 4 + j) * SGLD + sgc + 4] = b;
    }
  }
  __syncthreads();   // sgf visible

  const f32x4 z4 = {0.f, 0.f, 0.f, 0.f};
#pragma unroll 1
  for (int rr2 = 0; rr2 < 2; ++rr2) {
    const int rr = wv * 2 + rr2;          // 0..7 within block
    const int bl = r0 + rr;
    const float* dd = dbuf + (size_t)bl * KK;
    const float den0 = dd[lm] + po[lm];
    const float den1 = dd[16 + lm] + po[16 + lm];

#pragma unroll
    for (int khalf = 0; khalf < 2; ++khalf) {
      // A loads: re/im bf16 for (bl, k = khalf*16+lm), hp = lq*8..lq*8+7
      const int co = (khalf * 16 + lm) * 32 + lq * 8;
      const u16* rp = mbf + (size_t)bl * 2048 + co;
      s16x8 vre = *(const s16x8*)rp;
      s16x8 vim = *(const s16x8*)(rp + 1024);
      const float* pp = po + KK + co;
      float4 qa = *(const float4*)pp;
      float4 qb = *(const float4*)(pp + 4);
      float4 ja = *(const float4*)(pp + FLATC);
      float4 jb = *(const float4*)(pp + FLATC + 4);
      float re[8], im[8];
      re[0] = bf2f((u16)vre[0]) + qa.x; re[1] = bf2f((u16)vre[1]) + qa.y;
      re[2] = bf2f((u16)vre[2]) + qa.z; re[3] = bf2f((u16)vre[3]) + qa.w;
      re[4] = bf2f((u16)vre[4]) + qb.x; re[5] = bf2f((u16)vre[5]) + qb.y;
      re[6] = bf2f((u16)vre[6]) + qb.z; re[7] = bf2f((u16)vre[7]) + qb.w;
      im[0] = bf2f((u16)vim[0]) + ja.x; im[1] = bf2f((u16)vim[1]) + ja.y;
      im[2] = bf2f((u16)vim[2]) + ja.z; im[3] = bf2f((u16)vim[3]) + ja.w;
      im[4] = bf2f((u16)vim[4]) + jb.x; im[5] = bf2f((u16)vim[5]) + jb.y;
      im[6] = bf2f((u16)vim[6]) + jb.z; im[7] = bf2f((u16)vim[7]) + jb.w;

      float ssq = 0.f;
#pragma unroll
      for (int e = 0; e < 8; ++e) {
        ssq = fmaf(re[e], re[e], ssq);
        ssq = fmaf(im[e], im[e], ssq);
      }
      ssq += __shfl_xor(ssq, 16);
      ssq += __shfl_xor(ssq, 32);
      const float den = khalf ? den1 : den0;
      const float inv = 1.0f / fmaxf(den, 1e-4f);
      const float scale = inv * rsqrtf(ssq * inv * inv * (1.0f / 64.0f) + 1e-5f);

      s16x8 afr, afi;
#pragma unroll
      for (int e = 0; e < 8; ++e) {
        afr[e] = (short)f2bf(re[e] * scale);
        afi[e] = (short)f2bf(im[e] * scale);
      }

      f32x4 acc[2];
#pragma unroll
      for (int nt = 0; nt < 2; ++nt) {
        acc[nt] = __builtin_amdgcn_mfma_f32_16x16x32_bf16(afr, bre[nt], z4, 0, 0, 0);
        acc[nt] = __builtin_amdgcn_mfma_f32_16x16x32_bf16(afi, bim[nt], acc[nt], 0, 0, 0);
      }

      // epilogue: D row = lq*4+r (k offset), col = lm (h offset)
      u16* grow = g + (size_t)bl * 1024;
#pragma unroll
      for (int nt = 0; nt < 2; ++nt) {
#pragma unroll
        for (int r = 0; r < 4; ++r) {
          const int k = khalf * 16 + lq * 4 + r;
          const int o = k * 32 + nt * 16 + lm;
          const float sil = sgf[rr * SGLD + o + (o >> 7) * 8];
          grow[o] = f2bf(acc[nt][r] * sil);
        }
      }
    }
  }
}

// ---------------- launch ----------------
extern "C" void kernel_launch(void* const* d_in, const int* in_sizes, int n_in,
                              void* d_out, int out_size, void* d_ws, size_t ws_size,
                              hipStream_t stream) {
  const float* x      = (const float*)d_in[0];
  const float* W_in   = (const float*)d_in[1];
  const float* kern   = (const float*)d_in[2];
  const float* theta  = (const float*)d_in[3];
  const float* decay  = (const float*)d_in[4];
  const float* anchor = (const float*)d_in[5];
  const float* sscale = (const float*)d_in[6];
  const float* W_re   = (const float*)d_in[7];
  const float* W_im   = (const float*)d_in[8];
  const float* nscale = (const float*)d_in[9];
  const float* W_out  = (const float*)d_in[10];
  float* out = (float*)d_out;

  // workspace layout (173.3 MiB total; < proven 199 MiB budget):
  //   mbf  [BL][2048] u16  @ 0          (67.11 MB)  xbf aliases (dead pre-conv)
  //   zbf  [BL][ZLD]  u16  @ 67108864   (68.16 MB)
  //   dbuf [BL][32]   f32  @ 135266304  ( 2.10 MB)
  //   part [512][ZC]  f32  @ 137363456  ( 4.26 MB)
  //   wp   [2048]     u16  @ 141623296  ( 4 KB)
  //   wbt  [NPAD][DD] u16  @ 141627392  ( 4.46 MB)
  //   g    [BL][1024] u16  @ 146083840  (33.55 MB)
  //   wobt [DD][DD]   u16  @ 179638272  ( 2.10 MB)
  char* w = (char*)d_ws;
  u16* mbf   = (u16*)w;
  u16* xbf   = (u16*)w;                          // alias: dead once gemm1 done
  u16* zbf   = (u16*)(w + 67108864ull);
  float* dbuf = (float*)(w + 135266304ull);
  float* part = (float*)(w + 137363456ull);
  u16* wp    = (u16*)(w + 141623296ull);
  u16* wbt   = (u16*)(w + 141627392ull);
  u16* g     = (u16*)(w + 146083840ull);
  u16* wobt  = (u16*)(w + 179638272ull);

  // 1) fused prep: cast x + W_in^T + W_out^T + wprime (one dispatch)
  prep_kernel<<<dim3(8192 + 2176 + 1024 + 8), 256, 0, stream>>>(
      x, xbf, W_in, wbt, W_out, wobt, W_re, W_im, nscale, wp);

  // 2a) score cols 2048..2079 of z (tiny GEMM, keeps main grid clean)
  score_gemm<<<dim3(BL / 128), 256, 0, stream>>>(xbf, wbt, zbf);

  // 2b) GEMM1 main: z[:, :2048] = x @ W_in[:, :2048]. grid = 64x8 = 512
  // blocks = exactly 2 clean dispatch rounds at 1 block/CU.
  gemm256_8ph<1><<<dim3(BL / 256, 8), 512, 0, stream>>>(
      xbf, wbt, zbf, DD, DD, ZLD, DD, ZC);

  // 3) conv + p_w + features + chunk-local cumsum -> mbf(bf16), dbuf, part
  conv_feat_scan<<<dim3(BL / CCH), 256, 0, stream>>>(
      zbf, kern, theta, decay, anchor, sscale, mbf, dbuf, part);

  // 4) exclusive scan of chunk totals (in-place on part)
  {
    dim3 grid2((ZC + 255) / 256, 1, BB);
    scan_offsets_kernel<<<grid2, 256, 0, stream>>>(part);
  }

  // 5) normalize + RMS + head matmuls (MFMA) + gate -> g (compact bf16)
  norm_head_mfma<<<dim3(BL / 8), 256, 0, stream>>>(
      mbf, dbuf, zbf, kern, wp, part, g);

  // 6) GEMM2: out = g @ W_out (f32 out), lda = 1024 compact
  gemm256_8ph<0><<<dim3(BL / 256, DD / 256), 512, 0, stream>>>(
      g, wobt, out, 1024, DD, DD, DI, DD);
}

// Round 11
// 339.938 us; speedup vs baseline: 1.2154x; 1.0029x over previous
//
#include <hip/hip_runtime.h>
#include <hip/hip_bf16.h>
#include <math.h>

// ---------------- static problem config ----------------
#define BB 4
#define LL 4096
#define DD 1024
#define KK 32
#define HH 32
#define AA 4
#define CKK 4
#define DI 1024
#define ZC 2080            // 2*DI + KK
#define FLATC 1024         // K*H
#define BL (BB * LL)       // 16384
#define ZLD 2080           // z row stride (bf16)
#define NPAD 2176          // W_in^T padded rows (17*128)

// scan config: chunk == conv block == 32 rows
#define CCH 32
#define NCHK (LL / CCH)    // 128 chunks per b

// norm_head LDS strides (skewed to break lq-stride-128 bank conflicts)
#define GLD 1136           // zw row stride in u16 : col = o + (o>>7)*16
#define SGLD 1080          // sgf (silu-gate f32) row stride: col = o + (o>>7)*8

typedef unsigned short u16;
typedef __attribute__((ext_vector_type(8))) short s16x8;
typedef __attribute__((ext_vector_type(4))) float f32x4;

__device__ __forceinline__ u16 f2bf(float f) {
  union { float f; unsigned int u; } v; v.f = f;
  unsigned int r = (v.u + 0x7FFFu + ((v.u >> 16) & 1u)) >> 16;
  return (u16)r;
}
__device__ __forceinline__ float bf2f(u16 u) {
  union { unsigned int i; float f; } x; x.i = ((unsigned int)u) << 16; return x.f;
}
__device__ __forceinline__ void gl_lds16(const void* g, void* l) {
  __builtin_amdgcn_global_load_lds(
      (const __attribute__((address_space(1))) unsigned int*)g,
      (__attribute__((address_space(3))) unsigned int*)l, 16, 0, 0);
}

// ---------------- fused prep: cast x + W_in^T + W_out^T + wprime ----------
__global__ __launch_bounds__(256) void prep_kernel(
    const float* __restrict__ x, u16* __restrict__ xbf,
    const float* __restrict__ W_in, u16* __restrict__ wbt,
    const float* __restrict__ W_out, u16* __restrict__ wobt,
    const float* __restrict__ W_re, const float* __restrict__ W_im,
    const float* __restrict__ ns, u16* __restrict__ wp) {
  __shared__ float t[32][33];
  const int bid = blockIdx.x;
  const int tid = threadIdx.x;
  if (bid < 8192) {                       // cast x
    const int i = (bid * 256 + tid) * 8;
    float4 a = *(const float4*)(x + i);
    float4 b = *(const float4*)(x + i + 4);
    s16x8 v;
    v[0] = (short)f2bf(a.x); v[1] = (short)f2bf(a.y);
    v[2] = (short)f2bf(a.z); v[3] = (short)f2bf(a.w);
    v[4] = (short)f2bf(b.x); v[5] = (short)f2bf(b.y);
    v[6] = (short)f2bf(b.z); v[7] = (short)f2bf(b.w);
    *(s16x8*)(xbf + i) = v;
    return;
  }
  if (bid >= 8192 + 2176 + 1024) {        // wprime
    const int i = (bid - (8192 + 2176 + 1024)) * 256 + tid;
    if (i < 1024) wp[i] = f2bf(ns[i >> 5] * W_re[i]);
    else {
      const int j = i - 1024;
      wp[i] = f2bf(ns[32 + (j >> 5)] * W_im[j]);
    }
    return;
  }
  // transpose tiles
  const float* src; u16* dst; int R, C, Cpad, r0, c0;
  if (bid < 8192 + 2176) {
    const int id = bid - 8192;
    src = W_in; dst = wbt; R = DD; C = ZC; Cpad = NPAD;
    r0 = (id & 31) * 32; c0 = (id >> 5) * 32;
  } else {
    const int id = bid - (8192 + 2176);
    src = W_out; dst = wobt; R = DI; C = DD; Cpad = DD;
    r0 = (id & 31) * 32; c0 = (id >> 5) * 32;
  }
  const int lr = tid >> 5, lc = tid & 31;
#pragma unroll
  for (int i = 0; i < 4; ++i) {
    const int r = r0 + i * 8 + lr, c = c0 + lc;
    float v = 0.f;
    if (r < R && c < C) v = src[(size_t)r * C + c];
    t[lc][i * 8 + lr] = v;
  }
  __syncthreads();
#pragma unroll
  for (int i = 0; i < 4; ++i) {
    const int dr = c0 + i * 8 + lr;
    const int dc = r0 + lc;
    if (dr < Cpad && dc < R) dst[(size_t)dr * R + dc] = f2bf(t[i * 8 + lr][lc]);
  }
}

// ---------------- 256x256 8-phase bf16 MFMA GEMM (T1+T2+T3+T4+T5) --------
// C[M,N] = A[M,K] * Bt[N,K]^T.  512 threads = 8 waves (2M x 4N), per-wave
// output 128x64 (8x4 fragments of 16x16), BK=64, NT = K/64 tiles (even).
// Both call sites have EXACT full tiles (no column guards needed).
//
// LDS 128KB: 8 half-regions of 16KB (128 rows x 64 cols bf16, row-major).
// 3-bit XOR swizzle: elem_col ^= (row&7)<<3; conflict-free (verified:
// SQ_LDS_BANK_CONFLICT 7.08M -> 0). global_load_lds writes LINEAR dest,
// swizzle applied by pre-swizzling the GLOBAL source column (rule #21).
// Counted vmcnt(6) at phases 3/7 only; raw s_barrier (no vmcnt(0) drain).
//
// STAGED EPILOGUE (round 11): the old per-element epilogue issued 128
// scalar stores/thread in 32B(bf16)/64B(f32) row-strided chunks; counters
// showed BOTH gemms bound by WRITE bytes at ~700-870 GB/s effective
// (GEMM2 = GEMM1 duration at half the FLOPs, both ~66MB WRITE). After the
// K-loop the 128KB LDS is dead: stage the C-tile there (f32 in two
// 128-row halves) and emit fully-coalesced wide stores (per instruction a
// wave writes 1KB contiguous = complete 128B lines).
#define FENCE() asm volatile("" ::: "memory")
#define SBAR() do { FENCE(); __builtin_amdgcn_s_barrier(); FENCE(); } while (0)
#define VMCNT6() asm volatile("s_waitcnt vmcnt(6)" ::: "memory")

#define RA(s, h) (((s) * 2 + (h)) * 8192)
#define RB(s, h) (32768 + ((s) * 2 + (h)) * 8192)

template <int OUT_BF16>
__global__ __launch_bounds__(512, 2) void gemm256_8ph(
    const u16* __restrict__ A, const u16* __restrict__ Bt, void* __restrict__ C,
    int lda, int ldb, int ldc, int Kd, int Ncols) {
  __shared__ u16 lds[65536];   // 128 KiB
  const int tid = threadIdx.x;
  const int lane = tid & 63, wv = tid >> 6;
  const int wm = wv >> 2, wn = wv & 3;       // 2M x 4N wave grid
  const int lm = lane & 15, lq = lane >> 4;
  const int bm = blockIdx.x * 256, bn = blockIdx.y * 256;
  const int NT = Kd >> 6;                    // K tiles (even)
  const int NT2 = NT >> 1;

  const int rofs = wv * 8 + (lane >> 3);                 // region row
  const int cel = ((lane & 7) ^ (lane >> 3)) * 8;        // col elems, swz

  auto stageH = [&](const u16* __restrict__ G, int rowBase, int ld, int kt,
                    int regU16) {
    const u16* g0 = G + (size_t)(rowBase + rofs) * ld + (kt << 6) + cel;
    gl_lds16(g0, &lds[regU16 + wv * 512]);
    const u16* g1 = G + (size_t)(rowBase + 64 + rofs) * ld + (kt << 6) + cel;
    gl_lds16(g1, &lds[regU16 + 4096 + wv * 512]);
  };

  s16x8 Af[4][2], Bf[4][2];
  f32x4 acc[8][4];
  const f32x4 z4 = {0.f, 0.f, 0.f, 0.f};
#pragma unroll
  for (int i = 0; i < 8; ++i)
#pragma unroll
    for (int j = 0; j < 4; ++j) acc[i][j] = z4;

  const int xorw = (lm & 7) << 3;   // read-side swizzle XOR in u16 units

#define DSA(s, mh)                                                          \
  _Pragma("unroll") for (int f = 0; f < 4; ++f)                             \
  _Pragma("unroll") for (int ks = 0; ks < 2; ++ks)                          \
    Af[f][ks] = *(const s16x8*)&lds[RA(s, wm) +                             \
      (((((mh) * 4 + f) * 16 + lm) * 64 + ((ks * 32 + lq * 8) ^ xorw)))];

#define DSB(s)                                                              \
  _Pragma("unroll") for (int f = 0; f < 4; ++f)                             \
  _Pragma("unroll") for (int ks = 0; ks < 2; ++ks)                          \
    Bf[f][ks] = *(const s16x8*)&lds[RB(s, wn >> 1) +                        \
      ((((wn & 1) * 64 + f * 16 + lm) * 64 + ((ks * 32 + lq * 8) ^ xorw)))];

#define QUAD(mh, nh)                                                        \
  do {                                                                      \
    __builtin_amdgcn_s_setprio(1);                                          \
    _Pragma("unroll") for (int f = 0; f < 4; ++f)                           \
    _Pragma("unroll") for (int n = 0; n < 2; ++n)                           \
    _Pragma("unroll") for (int ks = 0; ks < 2; ++ks)                        \
      acc[(mh) * 4 + f][(nh) * 2 + n] =                                     \
          __builtin_amdgcn_mfma_f32_16x16x32_bf16(                          \
              Af[f][ks], Bf[(nh) * 2 + n][ks],                              \
              acc[(mh) * 4 + f][(nh) * 2 + n], 0, 0, 0);                    \
    __builtin_amdgcn_s_setprio(0);                                          \
  } while (0)

  // ---- prologue: 7 halves (t0 full + t1 B0,B1,A0); t1A1 comes at p0 ----
  stageH(A, bm, lda, 0, RA(0, 0));
  stageH(A, bm + 128, lda, 0, RA(0, 1));
  stageH(Bt, bn, ldb, 0, RB(0, 0));
  stageH(Bt, bn + 128, ldb, 0, RB(0, 1));
  stageH(Bt, bn, ldb, 1, RB(1, 0));
  stageH(Bt, bn + 128, ldb, 1, RB(1, 1));
  stageH(A, bm, lda, 1, RA(1, 0));
  VMCNT6();        // first 4 halves (tile 0) landed
  SBAR();

#pragma unroll 1
  for (int t = 0; t < NT2; ++t) {
    const int T2 = 2 * t + 2, T3 = 2 * t + 3;
    // -------- tile 2t from slot 0 --------
    DSA(0, 0); DSB(0);
    stageH(A, bm + 128, lda, 2 * t + 1, RA(1, 1));   // s1A1 of tile 2t+1
    SBAR();
    QUAD(0, 0);
    SBAR();
    if (T2 < NT) stageH(Bt, bn, ldb, T2, RB(0, 0));
    SBAR();
    QUAD(0, 1);
    SBAR();
    DSA(0, 1);
    if (T2 < NT) stageH(Bt, bn + 128, ldb, T2, RB(0, 1));
    SBAR();
    QUAD(1, 0);
    SBAR();
    if (T2 < NT) stageH(A, bm, lda, T2, RA(0, 0));
    SBAR();
    QUAD(1, 1);
    VMCNT6();      // slot1 (tile 2t+1) fully landed before p4 reads
    SBAR();
    // -------- tile 2t+1 from slot 1 --------
    DSA(1, 0); DSB(1);
    if (T2 < NT) stageH(A, bm + 128, lda, T2, RA(0, 1));
    SBAR();
    QUAD(0, 0);
    SBAR();
    if (T3 < NT) stageH(Bt, bn, ldb, T3, RB(1, 0));
    SBAR();
    QUAD(0, 1);
    SBAR();
    DSA(1, 1);
    if (T3 < NT) stageH(Bt, bn + 128, ldb, T3, RB(1, 1));
    SBAR();
    QUAD(1, 0);
    SBAR();
    if (T3 < NT) stageH(A, bm, lda, T3, RA(1, 0));
    SBAR();
    QUAD(1, 1);
    VMCNT6();      // slot0 (tile 2t+2) fully landed before next p0 reads
    SBAR();
  }

  // ---- staged epilogue: LDS tile -> coalesced wide stores ----
  asm volatile("s_waitcnt vmcnt(0)" ::: "memory");   // drain stray loads
  SBAR();                                            // lds now reusable
  if (OUT_BF16) {
    // full 256x256 bf16 tile = exactly 128 KB
#pragma unroll
    for (int f = 0; f < 8; ++f)
#pragma unroll
      for (int n = 0; n < 4; ++n)
#pragma unroll
        for (int r = 0; r < 4; ++r) {
          const int row = wm * 128 + f * 16 + lq * 4 + r;
          const int col = wn * 64 + n * 16 + lm;
          lds[row * 256 + col] = f2bf(acc[f][n][r]);
        }
    SBAR();
    // per instruction: wave writes 2 rows x 512B fully contiguous
#pragma unroll
    for (int it2 = 0; it2 < 16; ++it2) {
      const int row = it2 * 16 + wv * 2 + (lane >> 5);
      const int cb2 = (lane & 31) * 8;
      s16x8 v = *(const s16x8*)&lds[row * 256 + cb2];
      *(s16x8*)((u16*)C + (size_t)(bm + row) * ldc + bn + cb2) = v;
    }
  } else {
    // f32 tile = 256 KB: two 128-row halves of exactly 128 KB
    float* ldsf = (float*)lds;
#pragma unroll
    for (int h = 0; h < 2; ++h) {
      if (wm == h) {
#pragma unroll
        for (int f = 0; f < 8; ++f)
#pragma unroll
          for (int n = 0; n < 4; ++n)
#pragma unroll
            for (int r = 0; r < 4; ++r) {
              const int row = f * 16 + lq * 4 + r;   // local in half
              const int col = wn * 64 + n * 16 + lm;
              ldsf[row * 256 + col] = acc[f][n][r];
            }
      }
      SBAR();
      // per instruction: wave writes one full row (1KB contiguous)
#pragma unroll
      for (int it2 = 0; it2 < 16; ++it2) {
        const int row = it2 * 8 + wv;                // 0..127
        f32x4 v = *(const f32x4*)&ldsf[row * 256 + lane * 4];
        *(f32x4*)((float*)C + (size_t)(bm + h * 128 + row) * ldc + bn + lane * 4) = v;
      }
      SBAR();
    }
  }
#undef DSA
#undef DSB
#undef QUAD
}

// ---------------- score GEMM: z[:,2048:2080] = x @ W_in[:,2048:2080] -----
__global__ __launch_bounds__(256) void score_gemm(
    const u16* __restrict__ A, const u16* __restrict__ Bt,
    u16* __restrict__ z) {
  __shared__ u16 As[8192];   // 16 units x 512 elems (128 rows x 64 k)
  __shared__ u16 Bs[2048];   // 4 units  (32 rows x 64 k)
  const int tid = threadIdx.x;
  const int lane = tid & 63, wv = tid >> 6;
  const int lm = lane & 15, lq = lane >> 4;
  const int bm = blockIdx.x * 128;

  const f32x4 z4 = {0.f, 0.f, 0.f, 0.f};
  f32x4 acc[2][2];
#pragma unroll
  for (int i = 0; i < 2; ++i)
#pragma unroll
    for (int j = 0; j < 2; ++j) acc[i][j] = z4;

  for (int k0 = 0; k0 < DD; k0 += 64) {
    __syncthreads();
#pragma unroll
    for (int t = 0; t < 5; ++t) {
      const int idx = wv * 5 + t;            // 0..19
      if (idx < 16) {                        // A unit (mt, kt)
        const int mt = idx >> 1, kt = idx & 1;
        const u16* g = A + (size_t)(bm + mt * 16 + lm) * DD + k0 + kt * 32 + lq * 8;
        gl_lds16(g, &As[idx * 512]);
      } else {                               // B unit (nt, kt)
        const int bidx = idx - 16;
        const int nt = bidx >> 1, kt = bidx & 1;
        const u16* g = Bt + (size_t)(2048 + nt * 16 + lm) * DD + k0 + kt * 32 + lq * 8;
        gl_lds16(g, &Bs[bidx * 512]);
      }
    }
    __syncthreads();
#pragma unroll
    for (int kt = 0; kt < 2; ++kt) {
      s16x8 af[2], bfb[2];
#pragma unroll
      for (int i = 0; i < 2; ++i) {
        const int mt = wv * 2 + i;
        af[i] = *(const s16x8*)&As[(mt * 2 + kt) * 512 + lane * 8];
        bfb[i] = *(const s16x8*)&Bs[(i * 2 + kt) * 512 + lane * 8];
      }
#pragma unroll
      for (int i = 0; i < 2; ++i)
#pragma unroll
        for (int j = 0; j < 2; ++j)
          acc[i][j] = __builtin_amdgcn_mfma_f32_16x16x32_bf16(af[i], bfb[j], acc[i][j], 0, 0, 0);
    }
  }
#pragma unroll
  for (int i = 0; i < 2; ++i)
#pragma unroll
    for (int j = 0; j < 2; ++j)
#pragma unroll
      for (int r = 0; r < 4; ++r) {
        const int row = bm + wv * 32 + i * 16 + lq * 4 + r;
        const int col = 2048 + j * 16 + lm;
        z[(size_t)row * ZLD + col] = f2bf(acc[i][j][r]);
      }
}

// ---------------- conv + p_w + features + chunk-local cumsum --------------
// One block = one 32-row chunk. re/im chunk-local cumsums stored BF16
// (mbf [BL][2048]); den cumsum f32 in dbuf. Phase A reads the score
// columns from a vector-staged LDS panel (st).
__global__ __launch_bounds__(256) void conv_feat_scan(
    const u16* __restrict__ z, const float* __restrict__ kern,
    const float* __restrict__ theta, const float* __restrict__ decay,
    const float* __restrict__ anchor, const float* __restrict__ sscale,
    u16* __restrict__ mbf, float* __restrict__ dbuf,
    float* __restrict__ part) {
  __shared__ float pbuf[CCH][KK];   // raw p_w per (row, head)
  __shared__ u16 zt[35 * 256];      // staged z panel (17.5 KB)
  __shared__ u16 st[35 * 32];       // staged score panel (2.2 KB)
  const int tid = threadIdx.x;
  const int r0 = blockIdx.x * CCH;           // global row base
  const bool first = ((r0 & (LL - 1)) == 0);
  const int chunk = blockIdx.x;              // global chunk id

  // stage score panel rows r0-3 .. r0+31 (35 x 32 u16, vectorized)
  if (tid < 140) {
    const int row = tid >> 2, q8 = (tid & 3) * 8;
    s16x8 v = {0, 0, 0, 0, 0, 0, 0, 0};
    if (!(first && row < 3))
      v = *(const s16x8*)(z + (size_t)(r0 - 3 + row) * ZLD + 2048 + q8);
    *(s16x8*)&st[row * 32 + q8] = v;
  }
  __syncthreads();

  // phase A: p_w for 32 rows x 32 heads (4 items/thread), scores from LDS
#pragma unroll
  for (int q = 0; q < 4; ++q) {
    const int item = q * 256 + tid;
    const int row = item >> 5, k = item & 31;
    float v = 0.f;
#pragma unroll
    for (int w = 0; w < CKK; ++w)
      v = fmaf(bf2f(st[(row + w) * 32 + k]), kern[w * ZC + 2048 + k], v);
    const int l = (r0 + row) & (LL - 1);
    const float slope = (k < KK - AA) ? decay[k] : anchor[k - (KK - AA)];
    const float sp = log1pf(__expf(slope));
    const float lw = (k < KK - AA) ? (-sp * (float)(LL - 1 - l)) : (-sp * (float)l);
    pbuf[row][k] = __expf(sscale[k] * v + lw);
  }
  __syncthreads();

  // phase B: den chunk-local cumsum -> dbuf f32 (32 threads)
  if (tid < KK) {
    float run = 0.f;
#pragma unroll
    for (int row = 0; row < CCH; ++row) {
      run += pbuf[row][tid];
      dbuf[(size_t)(r0 + row) * KK + tid] = run;
    }
    part[(size_t)chunk * ZC + tid] = run;
  }

  // phase C: features + chunk-local cumsum. Per it: stage 35x256 panel
  // (vector loads), then rolling 4-tap conv from LDS.
#pragma unroll 1
  for (int it = 0; it < 4; ++it) {
    __syncthreads();   // protect zt reuse (and pbuf/phase-B on it==0)
    for (int u = tid; u < 35 * 32; u += 256) {
      const int row = u >> 5, q8 = (u & 31) * 8;
      s16x8 v = {0, 0, 0, 0, 0, 0, 0, 0};
      if (!(first && row < 3))
        v = *(const s16x8*)(z + (size_t)(r0 - 3 + row) * ZLD + it * 256 + q8);
      *(s16x8*)&zt[row * 256 + q8] = v;
    }
    __syncthreads();

    const int c = it * 256 + tid;            // 0..1023
    const float kw0 = kern[0 * ZC + c], kw1 = kern[1 * ZC + c];
    const float kw2 = kern[2 * ZC + c], kw3 = kern[3 * ZC + c];
    const float th = theta[c];
    const int head = c >> 5;
    float h0 = bf2f(zt[0 * 256 + tid]);
    float h1 = bf2f(zt[1 * 256 + tid]);
    float h2 = bf2f(zt[2 * 256 + tid]);
    float sre = 0.f, sim = 0.f;
#pragma unroll 4
    for (int row = 0; row < CCH; ++row) {
      const float h3 = bf2f(zt[(row + 3) * 256 + tid]);
      float v = h0 * kw0;
      v = fmaf(h1, kw1, v);
      v = fmaf(h2, kw2, v);
      v = fmaf(h3, kw3, v);
      h0 = h1; h1 = h2; h2 = h3;
      const float phi = v * th;
      float sv, cv;
      __sincosf(phi, &sv, &cv);
      const float p = pbuf[row][head];
      sre = fmaf(p, cv, sre);
      sim = fmaf(p, sv, sim);
      u16* mrow = mbf + (size_t)(r0 + row) * 2048;
      mrow[c] = f2bf(sre);
      mrow[1024 + c] = f2bf(sim);
    }
    part[(size_t)chunk * ZC + KK + c] = sre;
    part[(size_t)chunk * ZC + KK + FLATC + c] = sim;
  }
}

// ---------------- exclusive scan of chunk totals (128 chunks per b) -------
__global__ __launch_bounds__(256) void scan_offsets_kernel(float* __restrict__ part) {
  const int c = blockIdx.x * 256 + threadIdx.x;
  const int b = blockIdx.z;
  if (c >= ZC) return;
  float run = 0.f;
#pragma unroll 8
  for (int i = 0; i < NCHK; ++i) {
    const size_t idx = ((size_t)b * NCHK + i) * ZC + c;
    const float t = part[idx];
    part[idx] = run;
    run += t;
  }
}

// ---------------- norm_head via MFMA ----------------
// Block = 8 bl rows (4 waves x 2 rows). mbf holds CHUNK-LOCAL cumsum bf16;
// global prefix = bf2f(local) + part[chunk] (f32), den from dbuf f32.
// Gate phase-split: silu(conv(z_gate)) precomputed with vector LDS z reads
// + direct global kern f32 reads (34.5KB LDS -> 4 blocks/CU). sgf overlays
// the dead zw region. g written compact [BL][1024] bf16.
__global__ __launch_bounds__(256) void norm_head_mfma(
    const u16* __restrict__ mbf, const float* __restrict__ dbuf,
    const u16* __restrict__ z, const float* __restrict__ kern,
    const u16* __restrict__ wp, const float* __restrict__ part,
    u16* __restrict__ g) {
  // manual LDS partition: phase 1 zw (11*GLD*2 = 24992B);
  // phase 2 overlays sgf (8*SGLD*4 = 34560B) on the same region.
  __shared__ __align__(16) char smem[34560];
  u16* zw = (u16*)smem;                       // 11*GLD u16
  float* sgf = (float*)smem;                  // 8*SGLD f32 (overlay)
  const int tid = threadIdx.x;
  const int r0 = blockIdx.x * 8;
  const bool first = ((r0 & (LL - 1)) == 0);
  const int lane = tid & 63, wv = tid >> 6;
  const int lm = lane & 15, lq = lane >> 4;
  // chunk offsets row for this block (8 rows always within one 32-row chunk)
  const float* po = part + (size_t)(blockIdx.x >> 2) * ZC;

  // stage z gate cols (1024..2047), rows r0-3 .. r0+7, with skew
  for (int idx = tid; idx < 11 * 128; idx += 256) {
    const int i = idx >> 7, c8 = idx & 127;
    s16x8 v = {0, 0, 0, 0, 0, 0, 0, 0};
    if (!(first && i < 3))
      v = *(const s16x8*)(z + (size_t)(r0 - 3 + i) * ZLD + 1024 + c8 * 8);
    *(s16x8*)&zw[i * GLD + c8 * 8 + (c8 >> 4) * 16] = v;
  }

  // B fragments (same for all rows): lane(lm,lq) holds W'[lq*8+j][nt*16+lm]
  s16x8 bre[2], bim[2];
#pragma unroll
  for (int nt = 0; nt < 2; ++nt)
#pragma unroll
    for (int jj = 0; jj < 8; ++jj) {
      bre[nt][jj] = (short)wp[(lq * 8 + jj) * 32 + nt * 16 + lm];
      bim[nt][jj] = (short)wp[1024 + (lq * 8 + jj) * 32 + nt * 16 + lm];
    }
  __syncthreads();

  // ---- gate phase: silu(conv) for rows rh*4..+3, cols cb..cb+7 ----
  const int rh = tid >> 7;            // 0..1
  const int cb = (tid & 127) * 8;     // col base 0..1016
  float gbuf[4][8];
  {
    const int szb = cb + (cb >> 7) * 16;   // zw skewed col base
#pragma unroll
    for (int j = 0; j < 4; ++j) {
      const int rr = rh * 4 + j;
      float gv[8] = {0.f, 0.f, 0.f, 0.f, 0.f, 0.f, 0.f, 0.f};
#pragma unroll
      for (int w_ = 0; w_ < 4; ++w_) {
        s16x8 zv = *(const s16x8*)&zw[(rr + w_) * GLD + szb];
        float4 ka = *(const float4*)(kern + w_ * ZC + 1024 + cb);
        float4 kb = *(const float4*)(kern + w_ * ZC + 1024 + cb + 4);
        gv[0] = fmaf(bf2f((u16)zv[0]), ka.x, gv[0]);
        gv[1] = fmaf(bf2f((u16)zv[1]), ka.y, gv[1]);
        gv[2] = fmaf(bf2f((u16)zv[2]), ka.z, gv[2]);
        gv[3] = fmaf(bf2f((u16)zv[3]), ka.w, gv[3]);
        gv[4] = fmaf(bf2f((u16)zv[4]), kb.x, gv[4]);
        gv[5] = fmaf(bf2f((u16)zv[5]), kb.y, gv[5]);
        gv[6] = fmaf(bf2f((u16)zv[6]), kb.z, gv[6]);
        gv[7] = fmaf(bf2f((u16)zv[7]), kb.w, gv[7]);
      }
#pragma unroll
      for (int e = 0; e < 8; ++e)
        gbuf[j][e] = gv[e] * (1.0f / (1.0f + __expf(-gv[e])));
    }
  }
  __syncthreads();   // all zw reads complete (sgf overlays zw)
  {
    const int sgc = cb + (cb >> 7) * 8;    // sgf skewed col base
#pragma unroll
    for (int j = 0; j < 4; ++j) {
      float4 a = {gbuf[j][0], gbuf[j][1], gbuf[j][2], gbuf[j][3]};
      float4 b = {gbuf[j][4], gbuf[j][5], gbuf[j][6], gbuf[j][7]};
      *(float4*)&sgf[(rh * 4 + j) * SGLD + sgc] = a;
      *(float4*)&sgf[(rh * 4 + j) * SGLD + sgc + 4] = b;
    }
  }
  __syncthreads();   // sgf visible

  const f32x4 z4 = {0.f, 0.f, 0.f, 0.f};
#pragma unroll 1
  for (int rr2 = 0; rr2 < 2; ++rr2) {
    const int rr = wv * 2 + rr2;          // 0..7 within block
    const int bl = r0 + rr;
    const float* dd = dbuf + (size_t)bl * KK;
    const float den0 = dd[lm] + po[lm];
    const float den1 = dd[16 + lm] + po[16 + lm];

#pragma unroll
    for (int khalf = 0; khalf < 2; ++khalf) {
      // A loads: re/im bf16 for (bl, k = khalf*16+lm), hp = lq*8..lq*8+7
      const int co = (khalf * 16 + lm) * 32 + lq * 8;
      const u16* rp = mbf + (size_t)bl * 2048 + co;
      s16x8 vre = *(const s16x8*)rp;
      s16x8 vim = *(const s16x8*)(rp + 1024);
      const float* pp = po + KK + co;
      float4 qa = *(const float4*)pp;
      float4 qb = *(const float4*)(pp + 4);
      float4 ja = *(const float4*)(pp + FLATC);
      float4 jb = *(const float4*)(pp + FLATC + 4);
      float re[8], im[8];
      re[0] = bf2f((u16)vre[0]) + qa.x; re[1] = bf2f((u16)vre[1]) + qa.y;
      re[2] = bf2f((u16)vre[2]) + qa.z; re[3] = bf2f((u16)vre[3]) + qa.w;
      re[4] = bf2f((u16)vre[4]) + qb.x; re[5] = bf2f((u16)vre[5]) + qb.y;
      re[6] = bf2f((u16)vre[6]) + qb.z; re[7] = bf2f((u16)vre[7]) + qb.w;
      im[0] = bf2f((u16)vim[0]) + ja.x; im[1] = bf2f((u16)vim[1]) + ja.y;
      im[2] = bf2f((u16)vim[2]) + ja.z; im[3] = bf2f((u16)vim[3]) + ja.w;
      im[4] = bf2f((u16)vim[4]) + jb.x; im[5] = bf2f((u16)vim[5]) + jb.y;
      im[6] = bf2f((u16)vim[6]) + jb.z; im[7] = bf2f((u16)vim[7]) + jb.w;

      float ssq = 0.f;
#pragma unroll
      for (int e = 0; e < 8; ++e) {
        ssq = fmaf(re[e], re[e], ssq);
        ssq = fmaf(im[e], im[e], ssq);
      }
      ssq += __shfl_xor(ssq, 16);
      ssq += __shfl_xor(ssq, 32);
      const float den = khalf ? den1 : den0;
      const float inv = 1.0f / fmaxf(den, 1e-4f);
      const float scale = inv * rsqrtf(ssq * inv * inv * (1.0f / 64.0f) + 1e-5f);

      s16x8 afr, afi;
#pragma unroll
      for (int e = 0; e < 8; ++e) {
        afr[e] = (short)f2bf(re[e] * scale);
        afi[e] = (short)f2bf(im[e] * scale);
      }

      f32x4 acc[2];
#pragma unroll
      for (int nt = 0; nt < 2; ++nt) {
        acc[nt] = __builtin_amdgcn_mfma_f32_16x16x32_bf16(afr, bre[nt], z4, 0, 0, 0);
        acc[nt] = __builtin_amdgcn_mfma_f32_16x16x32_bf16(afi, bim[nt], acc[nt], 0, 0, 0);
      }

      // epilogue: D row = lq*4+r (k offset), col = lm (h offset)
      u16* grow = g + (size_t)bl * 1024;
#pragma unroll
      for (int nt = 0; nt < 2; ++nt) {
#pragma unroll
        for (int r = 0; r < 4; ++r) {
          const int k = khalf * 16 + lq * 4 + r;
          const int o = k * 32 + nt * 16 + lm;
          const float sil = sgf[rr * SGLD + o + (o >> 7) * 8];
          grow[o] = f2bf(acc[nt][r] * sil);
        }
      }
    }
  }
}

// ---------------- launch ----------------
extern "C" void kernel_launch(void* const* d_in, const int* in_sizes, int n_in,
                              void* d_out, int out_size, void* d_ws, size_t ws_size,
                              hipStream_t stream) {
  const float* x      = (const float*)d_in[0];
  const float* W_in   = (const float*)d_in[1];
  const float* kern   = (const float*)d_in[2];
  const float* theta  = (const float*)d_in[3];
  const float* decay  = (const float*)d_in[4];
  const float* anchor = (const float*)d_in[5];
  const float* sscale = (const float*)d_in[6];
  const float* W_re   = (const float*)d_in[7];
  const float* W_im   = (const float*)d_in[8];
  const float* nscale = (const float*)d_in[9];
  const float* W_out  = (const float*)d_in[10];
  float* out = (float*)d_out;

  // workspace layout (173.3 MiB total; < proven 199 MiB budget):
  //   mbf  [BL][2048] u16  @ 0          (67.11 MB)  xbf aliases (dead pre-conv)
  //   zbf  [BL][ZLD]  u16  @ 67108864   (68.16 MB)
  //   dbuf [BL][32]   f32  @ 135266304  ( 2.10 MB)
  //   part [512][ZC]  f32  @ 137363456  ( 4.26 MB)
  //   wp   [2048]     u16  @ 141623296  ( 4 KB)
  //   wbt  [NPAD][DD] u16  @ 141627392  ( 4.46 MB)
  //   g    [BL][1024] u16  @ 146083840  (33.55 MB)
  //   wobt [DD][DD]   u16  @ 179638272  ( 2.10 MB)
  char* w = (char*)d_ws;
  u16* mbf   = (u16*)w;
  u16* xbf   = (u16*)w;                          // alias: dead once gemm1 done
  u16* zbf   = (u16*)(w + 67108864ull);
  float* dbuf = (float*)(w + 135266304ull);
  float* part = (float*)(w + 137363456ull);
  u16* wp    = (u16*)(w + 141623296ull);
  u16* wbt   = (u16*)(w + 141627392ull);
  u16* g     = (u16*)(w + 146083840ull);
  u16* wobt  = (u16*)(w + 179638272ull);

  // 1) fused prep: cast x + W_in^T + W_out^T + wprime (one dispatch)
  prep_kernel<<<dim3(8192 + 2176 + 1024 + 8), 256, 0, stream>>>(
      x, xbf, W_in, wbt, W_out, wobt, W_re, W_im, nscale, wp);

  // 2a) score cols 2048..2079 of z (tiny GEMM, keeps main grid clean)
  score_gemm<<<dim3(BL / 128), 256, 0, stream>>>(xbf, wbt, zbf);

  // 2b) GEMM1 main: z[:, :2048] = x @ W_in[:, :2048]. grid = 64x8 = 512
  // blocks = exactly 2 clean dispatch rounds at 1 block/CU.
  gemm256_8ph<1><<<dim3(BL / 256, 8), 512, 0, stream>>>(
      xbf, wbt, zbf, DD, DD, ZLD, DD, ZC);

  // 3) conv + p_w + features + chunk-local cumsum -> mbf(bf16), dbuf, part
  conv_feat_scan<<<dim3(BL / CCH), 256, 0, stream>>>(
      zbf, kern, theta, decay, anchor, sscale, mbf, dbuf, part);

  // 4) exclusive scan of chunk totals (in-place on part)
  {
    dim3 grid2((ZC + 255) / 256, 1, BB);
    scan_offsets_kernel<<<grid2, 256, 0, stream>>>(part);
  }

  // 5) normalize + RMS + head matmuls (MFMA) + gate -> g (compact bf16)
  norm_head_mfma<<<dim3(BL / 8), 256, 0, stream>>>(
      mbf, dbuf, zbf, kern, wp, part, g);

  // 6) GEMM2: out = g @ W_out (f32 out), lda = 1024 compact
  gemm256_8ph<0><<<dim3(BL / 256, DD / 256), 512, 0, stream>>>(
      g, wobt, out, 1024, DD, DD, DI, DD);
}